// Round 10
// baseline (7263.947 us; speedup 1.0000x reference)
//
#include <hip/hip_runtime.h>
#include <hip/hip_bf16.h>

// PhasedLSTM classifier: persistent cooperative kernel, 2-chain pipeline.
// 16 groups (16 samples) x 32 slices; 256 blocks; block = (pair p, slice),
// handles chains A=group 2p, B=2p+1 (same weight slice -> shared VGPR wr).
// Half-iter: MFMA_Y (waves0-5) || poll+DMA+stats_X (waves6-7); bar;
// combine_Y (waves0-3, X-DMA in flight); bar(drain); post_Y, head_Y.
// Exchange: relaxed agent-scope atomics + G2L(aux=16) DMA (proven R9).

#define NB 256
#define NTHR 512
#define T_STEPS 500
#define RON 0.05f
#define ALPHA_LEAK 1e-3f

typedef short short8 __attribute__((ext_vector_type(8)));
typedef float f32x4 __attribute__((ext_vector_type(4)));
typedef unsigned long long ull;

// ---------------- ws layout (bytes) ----------------
#define OFF_WSWZ 0u              // 6291456  swizzled bf16 weights
#define OFF_U1   6291456u        // 8192
#define OFF_V1   6299648u        // 8192
#define OFF_WFP  6307840u        // 20480    Wf' permuted [kk][c][lane] f32
#define OFF_UFV  6328320u        // 128
#define OFF_H0B  6328448u        // 524288   [2][16 grp][8192 shorts] frag16 order
#define OFF_H1B  6852736u        // 524288
#define OFF_ST0  7377024u        // 131072   [2][16][16 m][32 sl][2] f32
#define OFF_ST1  7508096u        // 131072
#define OFF_FLG  7639168u        // 2048     [16 grp][32 sl] u32 round flags
#define ZERO_BYTES 1312768u      // OFF_H0B .. OFF_FLG+2048

// ---------------- LDS layout (bytes) ----------------
// 0      h0bA 16384 | 16384 h0bB 16384
// 32768  h1bA[2] 32768 | 65536 h1bB[2] 32768
// 98304  zbv 13056 (3 x [16][67] f32, stride-pad 1088 floats/mm)
// 111360 stA 4096 | 115456 stB 4096   (h0f,c0f,h1f,c1f x 256 f32)
// 119552 muA 256 | 119808 muB 256     (mu0,rs0,mu1,rs1 x 16)
// 120064 prm 2048 | 122112 wfl 20480 | 142592 ufl 128
// 142720 xtA 512 | 143232 xtB 512
#define SMEM_BYTES 143872

#define AT_LD(p)    __hip_atomic_load((p), __ATOMIC_RELAXED, __HIP_MEMORY_SCOPE_AGENT)
#define AT_ST(p, v) __hip_atomic_store((p), (v), __ATOMIC_RELAXED, __HIP_MEMORY_SCOPE_AGENT)

#define G2L(gp, lp) \
  __builtin_amdgcn_global_load_lds( \
      (const __attribute__((address_space(1))) void*)(gp), \
      (__attribute__((address_space(3))) void*)(lp), 16, 0, 16)

__device__ __forceinline__ short f2bf(float x) {
  unsigned u = __float_as_uint(x);
  unsigned r = (u + 0x7fffu + ((u >> 16) & 1u)) >> 16;
  return (short)r;
}
__device__ __forceinline__ float bf2f(short s) {
  return __uint_as_float(((unsigned)(unsigned short)s) << 16);
}
__device__ __forceinline__ float sigm(float x) { return 1.f / (1.f + __expf(-x)); }
__device__ __forceinline__ float tanh_f(float x) {
  float cx = fminf(fmaxf(x, -15.f), 15.f);
  float e = __expf(2.f * cx);
  return (e - 1.f) / (e + 1.f);
}
__device__ __forceinline__ float timegate(float t, float tau, float s) {
  float phi = fmodf(t - s, tau);
  if (phi < 0.f) phi += tau;
  phi /= tau;
  return phi < 0.5f * RON ? (2.f / RON) * phi
       : (phi < RON ? 2.f - (2.f / RON) * phi : ALPHA_LEAK * phi);
}
// element index (shorts) of (sample m<16, unit k<512) in a [16][512] bf16
// buffer stored in 16x16x32-MFMA A-fragment order.
__device__ __forceinline__ int fragidx16(int m, int k) {
  return ((k >> 5) * 64 + ((k >> 3) & 3) * 16 + m) * 8 + (k & 7);
}

// ---------------- prep kernels (unchanged layouts) ----------------
__global__ void prep_weights(const float* __restrict__ R0, const float* __restrict__ W1,
                             const float* __restrict__ R1, const float* __restrict__ g0,
                             short* __restrict__ Wswz) {
  int t = blockIdx.x * 256 + threadIdx.x;   // < 393216
  int lane = t & 63; int rest = t >> 6;
  int nf = rest & 1;  rest >>= 1;
  int kb = rest & 15; rest >>= 4;
  int ch = rest & 1;  rest >>= 1;
  int mm = rest % 3;  int slice = rest / 3;
  int c = ch * 32 + nf * 16 + (lane & 15);
  int gate = c >> 4;
  int unit = slice * 16 + (c & 15);
  int gcol = gate * 512 + unit;
  int k0 = kb * 32 + (lane >> 4) * 8;
  const float* src = (mm == 0) ? R0 : (mm == 1 ? W1 : R1);
  short8 o;
  #pragma unroll
  for (int e = 0; e < 8; ++e) {
    float v = src[(size_t)(k0 + e) * 2048 + gcol];
    if (mm == 1) v *= g0[k0 + e];
    o[e] = f2bf(v);
  }
  *(short8*)(Wswz + (size_t)t * 8) = o;
}

__global__ void prep_vecs(const float* __restrict__ W1, const float* __restrict__ g0,
                          const float* __restrict__ be0,
                          float* __restrict__ u1, float* __restrict__ v1) {
  int c = blockIdx.x * 256 + threadIdx.x;  // < 2048
  float su = 0.f, sv = 0.f;
  for (int k = 0; k < 512; ++k) {
    float w = W1[(size_t)k * 2048 + c];
    su += be0[k] * w; sv += g0[k] * w;
  }
  u1[c] = su; v1[c] = sv;
}

__global__ void prep_head(const float* __restrict__ Wf, const float* __restrict__ g1,
                          const float* __restrict__ be1, const float* __restrict__ bfv,
                          float* __restrict__ Wfp, float* __restrict__ ufv) {
  int t = blockIdx.x * 256 + threadIdx.x;
  if (t < 5120) {
    int kk = t / 640, rem = t - kk * 640, c = rem >> 6, l = rem & 63;
    int k = 8 * l + kk;
    Wfp[t] = g1[k] * Wf[k * 10 + c];
  }
  if (t < 10) {
    float su = bfv[t], sv = 0.f;
    for (int k = 0; k < 512; ++k) {
      float w = Wf[k * 10 + t];
      su += be1[k] * w; sv += g1[k] * w;
    }
    ufv[t] = su; ufv[16 + t] = sv;
  }
}

// ---------------- persistent kernel ----------------
struct Ptrs {
  const float *x, *times, *W0, *b0, *tau0, *s0, *b1, *tau1, *s1;
  const float *u1v, *v1v, *Wfp, *ufv;
  short *H0b, *H1b;
  float *St0, *St1;
  unsigned *flag;
  float *out;
};

__launch_bounds__(NTHR, 1)
__global__ void plstm_persist(Ptrs P, const short* __restrict__ Wswz) {
  extern __shared__ char smem[];
  short* h0bs[2] = {(short*)smem, (short*)(smem + 16384)};
  short* h1bs[2] = {(short*)(smem + 32768), (short*)(smem + 65536)}; // [2 slot][8192]
  float* zbv    = (float*)(smem + 98304);
  float* sts[2] = {(float*)(smem + 111360), (float*)(smem + 115456)};
  float* mus[2] = {(float*)(smem + 119552), (float*)(smem + 119808)};
  float* prm    = (float*)(smem + 120064);
  float* wfl    = (float*)(smem + 122112);
  float* ufl    = (float*)(smem + 142592);
  float* xts[2] = {(float*)(smem + 142720), (float*)(smem + 143232)};

  const int tid = threadIdx.x;
  const int pair = blockIdx.x & 7;
  const int slice = blockIdx.x >> 3;
  const int wid = tid >> 6, lane = tid & 63;
  const int mm = wid >> 1, ch = wid & 1;
  const int qgrp[2] = {pair * 2, pair * 2 + 1};

  // ---- one-time LDS init ----
  for (int i = tid; i < 1024; i += NTHR) { sts[0][i] = 0.f; }
  for (int i = tid; i < 1024; i += NTHR) { sts[1][i] = 0.f; }
  for (int i = tid; i < 512; i += NTHR) {
    float v;
    if (i < 192)      { int f = i >> 6, c = i & 63; v = P.W0[f * 2048 + ((c >> 4) << 9) + slice * 16 + (c & 15)]; }
    else if (i < 256) { int c = i & 63; v = P.b0[((c >> 4) << 9) + slice * 16 + (c & 15)]; }
    else if (i < 320) { int c = i & 63; int gc = ((c >> 4) << 9) + slice * 16 + (c & 15);
                        v = P.b1[gc] + P.u1v[gc]; }
    else if (i < 384) { int c = i & 63; v = P.v1v[((c >> 4) << 9) + slice * 16 + (c & 15)]; }
    else if (i < 448) v = 0.f;
    else if (i < 464) v = P.tau0[slice * 16 + (i & 15)];
    else if (i < 480) v = P.s0[slice * 16 + (i & 15)];
    else if (i < 496) v = P.tau1[slice * 16 + (i & 15)];
    else              v = P.s1[slice * 16 + (i & 15)];
    prm[i] = v;
  }
  for (int i = tid; i < 5120; i += NTHR) wfl[i] = P.Wfp[i];
  if (tid < 32) ufl[tid] = P.ufv[tid];

  // ---- resident weights (waves 0-5): 16 kb x 2 nf short8 = 128 VGPRs ----
  short8 wr[16][2];
  if (wid < 6) {
    const short* wb = Wswz + ((((size_t)slice * 3 + mm) * 2 + ch) * 32 * 64) * 8;
    #pragma unroll
    for (int kb = 0; kb < 16; ++kb)
      #pragma unroll
      for (int nf = 0; nf < 2; ++nf) {
        wr[kb][nf] = *(const short8*)(wb + ((kb * 2 + nf) * 64 + lane) * 8);
        asm volatile("" : "+v"(wr[kb][nf]));
      }
  }
  __syncthreads();

  for (int i = 0; i <= T_STEPS + 2; ++i) {   // 503 iterations
    #pragma unroll
    for (int h = 0; h < 2; ++h) {
      const int X = h, Y = h ^ 1;
      const int rs_ = i;                       // stage round for chain X
      const int rc_ = (h == 0) ? i - 1 : i;    // compute round for chain Y
      const bool sv  = (rs_ <= T_STEPS + 1);
      const bool cv  = (rc_ >= 0 && rc_ <= T_STEPS + 1);
      const bool mfv = (rc_ >= 0 && rc_ <= T_STEPS);
      const int qX = qgrp[X], qY = qgrp[Y];

      // ---- phase 1: MFMA_Y (waves 0-5) || poll+DMA/stats_X (waves 6-7) ----
      if (wid < 6) {
        if (mfv) {
          f32x4 acc[2] = {};
          const short* asrc = (mm == 2) ? (h1bs[Y] + (rc_ & 1) * 8192) : h0bs[Y];
          #pragma unroll
          for (int kb = 0; kb < 16; ++kb) {
            short8 a = *(const short8*)(asrc + (kb * 64 + lane) * 8);
            acc[0] = __builtin_amdgcn_mfma_f32_16x16x32_bf16(a, wr[kb][0], acc[0], 0, 0, 0);
            acc[1] = __builtin_amdgcn_mfma_f32_16x16x32_bf16(a, wr[kb][1], acc[1], 0, 0, 0);
          }
          float* z = zbv + mm * 1088;
          #pragma unroll
          for (int nf = 0; nf < 2; ++nf)
            #pragma unroll
            for (int q = 0; q < 4; ++q)
              z[((lane >> 4) * 4 + q) * 67 + ch * 32 + nf * 16 + (lane & 15)] = acc[nf][q];
        }
      } else if (sv) {
        // both waves 6 & 7 poll chain X's flags (monotonic, bounded)
        {
          const unsigned tgt = (unsigned)rs_;
          const unsigned* fp = P.flag + qX * 32 + (lane & 31);
          for (int it_ = 0; it_ < 100000; ++it_) {
            unsigned v = (lane < 32) ? AT_LD(fp) : 0xFFFFFFFFu;
            if (__all((int)(v >= tgt))) break;
            __builtin_amdgcn_s_sleep(1);
          }
        }
        const int bufAs = (rs_ + 1) & 1, bufBs = rs_ & 1;
        if (wid == 6) {
          const char* gA = (const char*)(P.H0b + ((size_t)bufAs * 16 + qX) * 8192);
          const char* gB = (const char*)(P.H1b + ((size_t)bufBs * 16 + qX) * 8192);
          char* lA = (char*)h0bs[X];
          char* lB = (char*)(h1bs[X] + (rs_ & 1) * 8192);
          #pragma unroll
          for (int j = 0; j < 16; ++j) {
            unsigned off = j * 1024u + (unsigned)lane * 16u;
            G2L(gA + off, lA + off);
            G2L(gB + off, lB + off);
          }
          int m = lane & 15;
          if (lane < 16) {
            int step = (rs_ < T_STEPS) ? rs_ : (T_STEPS - 1);
            const float* xp = P.x + ((size_t)(qX * 16 + m) * T_STEPS + step) * 3;
            float* xt = xts[X];
            xt[m * 4 + 0] = xp[0]; xt[m * 4 + 1] = xp[1]; xt[m * 4 + 2] = xp[2];
            xt[m * 4 + 3] = P.times[(size_t)(qX * 16 + m) * T_STEPS + step];
          } else if (lane < 32) {
            int s1_ = (rs_ >= 1) ? rs_ - 1 : 0;
            if (s1_ > T_STEPS - 1) s1_ = T_STEPS - 1;
            xts[X][64 + m] = P.times[(size_t)(qX * 16 + m) * T_STEPS + s1_];
          }
        } else {  // wid == 7: LN stats finalize for X
          const int layer = lane >> 5, m = lane & 31;
          if (m < 16) {
            const float* base = layer
                ? (P.St1 + ((size_t)bufBs * 16 + qX) * 1024 + m * 64)
                : (P.St0 + ((size_t)bufAs * 16 + qX) * 1024 + m * 64);
            const ull* bu = (const ull*)base;
            float s_ = 0.f, q_ = 0.f;
            #pragma unroll
            for (int sl = 0; sl < 32; ++sl) {
              ull v = AT_LD(bu + sl);
              s_ += __uint_as_float((unsigned)v);
              q_ += __uint_as_float((unsigned)(v >> 32));
            }
            float mu = s_ * (1.f / 512.f);
            float var = q_ * (1.f / 512.f) - mu * mu;
            mus[X][layer * 32 + m] = mu;
            mus[X][layer * 32 + 16 + m] = rsqrtf(var + 1e-3f);
          }
        }
      }
      __syncthreads();   // bar1: zbv ready; murs_X ready; DMA_X in flight

      // ---- phase 2: combine_Y (waves 0-3; 2 cells each) ----
      if (mfv && tid < 256) {
        const int bufAc = (rc_ + 1) & 1, bufBc = rc_ & 1;
        const int layer = tid >> 7;
        const int idx = tid & 127;
        const int m = idx >> 3, u0 = (idx & 7) << 1;
        const bool act = (layer == 0) ? (rc_ < T_STEPS) : (rc_ >= 1);
        if (act) {
          float* st = sts[Y];
          float hnv[2]; unsigned pack = 0;
          if (layer == 0) {
            const float* xt = xts[Y];
            float x0 = xt[m * 4], x1 = xt[m * 4 + 1], x2 = xt[m * 4 + 2], tmv = xt[m * 4 + 3];
            #pragma unroll
            for (int uu = 0; uu < 2; ++uu) {
              int u = u0 + uu, id = m * 16 + u;
              float zg[4];
              #pragma unroll
              for (int q = 0; q < 4; ++q) {
                int c = q * 16 + u;
                zg[q] = zbv[m * 67 + c] + prm[192 + c]
                      + x0 * prm[c] + x1 * prm[64 + c] + x2 * prm[128 + c];
              }
              float iv = sigm(zg[0]), fv = sigm(zg[1]), gv = tanh_f(zg[2]), ov = sigm(zg[3]);
              float cold = st[256 + id], hold = st[id];
              float cp = fv * cold + iv * gv;
              float hp = ov * tanh_f(cp);
              float k = timegate(tmv, prm[448 + u], prm[464 + u]);
              float hn = k * hp + (1.f - k) * hold;
              float cn = k * cp + (1.f - k) * cold;
              st[id] = hn; st[256 + id] = cn; hnv[uu] = hn;
              pack |= ((unsigned)(unsigned short)f2bf(hn)) << (16 * uu);
            }
            AT_ST((unsigned*)(P.H0b + ((size_t)bufBc * 16 + qY) * 8192 + fragidx16(m, slice * 16 + u0)), pack);
            float sr = hnv[0] + hnv[1], qr = hnv[0] * hnv[0] + hnv[1] * hnv[1];
            sr += __shfl_down(sr, 4, 8); qr += __shfl_down(qr, 4, 8);
            sr += __shfl_down(sr, 2, 8); qr += __shfl_down(qr, 2, 8);
            sr += __shfl_down(sr, 1, 8); qr += __shfl_down(qr, 1, 8);
            if ((idx & 7) == 0) {
              ull pv = ((ull)__float_as_uint(qr) << 32) | __float_as_uint(sr);
              AT_ST((ull*)(P.St0 + ((size_t)bufBc * 16 + qY) * 1024) + m * 32 + slice, pv);
            }
          } else {
            float mu0m = mus[Y][m], rs0m = mus[Y][16 + m];
            float tmv = xts[Y][64 + m];
            #pragma unroll
            for (int uu = 0; uu < 2; ++uu) {
              int u = u0 + uu, id = m * 16 + u;
              float zg[4];
              #pragma unroll
              for (int q = 0; q < 4; ++q) {
                int c = q * 16 + u;
                float zA = zbv[1088 + m * 67 + c];   // h0 @ (g0.W1)
                float zB = zbv[2176 + m * 67 + c];   // h1 @ R1
                zg[q] = rs0m * zA + zB + prm[256 + c] - mu0m * rs0m * prm[320 + c];
              }
              float iv = sigm(zg[0]), fv = sigm(zg[1]), gv = tanh_f(zg[2]), ov = sigm(zg[3]);
              float cold = st[768 + id], hold = st[512 + id];
              float cp = fv * cold + iv * gv;
              float hp = ov * tanh_f(cp);
              float k = timegate(tmv, prm[480 + u], prm[496 + u]);
              float hn = k * hp + (1.f - k) * hold;
              float cn = k * cp + (1.f - k) * cold;
              st[512 + id] = hn; st[768 + id] = cn; hnv[uu] = hn;
              pack |= ((unsigned)(unsigned short)f2bf(hn)) << (16 * uu);
            }
            AT_ST((unsigned*)(P.H1b + ((size_t)bufAc * 16 + qY) * 8192 + fragidx16(m, slice * 16 + u0)), pack);
            float sr = hnv[0] + hnv[1], qr = hnv[0] * hnv[0] + hnv[1] * hnv[1];
            sr += __shfl_down(sr, 4, 8); qr += __shfl_down(qr, 4, 8);
            sr += __shfl_down(sr, 2, 8); qr += __shfl_down(qr, 2, 8);
            sr += __shfl_down(sr, 1, 8); qr += __shfl_down(qr, 1, 8);
            if ((idx & 7) == 0) {
              ull pv = ((ull)__float_as_uint(qr) << 32) | __float_as_uint(sr);
              AT_ST((ull*)(P.St1 + ((size_t)bufAc * 16 + qY) * 1024) + m * 32 + slice, pv);
            }
          }
        }
      }
      __syncthreads();   // cbar: drains combine stores AND DMA_X

      // ---- post_Y + head_Y (off critical path) ----
      if (cv) {
        if (tid == 0 && rc_ <= T_STEPS)
          AT_ST(P.flag + qY * 32 + slice, (unsigned)(rc_ + 1));
        if (wid == 7 && rc_ >= 2) {
          const int msam = slice & 15;
          const short* h1r = h1bs[Y] + (rc_ & 1) * 8192;
          short8 hv8 = *(const short8*)(h1r + fragidx16(msam, lane * 8));
          float lg[10];
          #pragma unroll
          for (int c = 0; c < 10; ++c) lg[c] = 0.f;
          #pragma unroll
          for (int kk = 0; kk < 8; ++kk) {
            float hv = bf2f(hv8[kk]);
            const float* wf = wfl + kk * 640 + lane;
            #pragma unroll
            for (int c = 0; c < 10; ++c) lg[c] += hv * wf[c * 64];
          }
          #pragma unroll
          for (int off = 32; off > 0; off >>= 1)
            #pragma unroll
            for (int c = 0; c < 10; ++c) lg[c] += __shfl_down(lg[c], off, 64);
          if (lane == 0) {
            float m1 = mus[Y][32 + msam], r1 = mus[Y][48 + msam];
            float logit[10], mx = -1e30f;
            #pragma unroll
            for (int c = 0; c < 10; ++c) {
              logit[c] = r1 * lg[c] + ufl[c] - m1 * r1 * ufl[16 + c];
              mx = fmaxf(mx, logit[c]);
            }
            float ssum = 0.f;
            #pragma unroll
            for (int c = 0; c < 10; ++c) { logit[c] = expf(logit[c] - mx); ssum += logit[c]; }
            float inv = 1.f / ssum;
            float* op = P.out + ((size_t)(qY * 16 + msam) * T_STEPS + (rc_ - 2)) * 10;
            #pragma unroll
            for (int c = 0; c < 10; ++c) op[c] = logit[c] * inv;
          }
        }
      }
    }
  }
}

extern "C" void kernel_launch(void* const* d_in, const int* in_sizes, int n_in,
                              void* d_out, int out_size, void* d_ws, size_t ws_size,
                              hipStream_t stream) {
  const float* x    = (const float*)d_in[0];
  const float* tms  = (const float*)d_in[1];
  const float* W0   = (const float*)d_in[2];
  const float* R0   = (const float*)d_in[3];
  const float* b0   = (const float*)d_in[4];
  const float* tau0 = (const float*)d_in[5];
  const float* s0   = (const float*)d_in[6];
  const float* g0   = (const float*)d_in[7];
  const float* be0  = (const float*)d_in[8];
  const float* W1   = (const float*)d_in[9];
  const float* R1   = (const float*)d_in[10];
  const float* b1   = (const float*)d_in[11];
  const float* tau1 = (const float*)d_in[12];
  const float* s1   = (const float*)d_in[13];
  const float* g1   = (const float*)d_in[14];
  const float* be1  = (const float*)d_in[15];
  const float* Wf   = (const float*)d_in[16];
  const float* bfv  = (const float*)d_in[17];

  char* ws = (char*)d_ws;
  short* Wswz = (short*)(ws + OFF_WSWZ);
  float* u1m  = (float*)(ws + OFF_U1);
  float* v1m  = (float*)(ws + OFF_V1);
  float* Wfpm = (float*)(ws + OFF_WFP);
  float* ufvm = (float*)(ws + OFF_UFV);

  Ptrs P;
  P.x = x; P.times = tms; P.W0 = W0; P.b0 = b0; P.tau0 = tau0; P.s0 = s0;
  P.b1 = b1; P.tau1 = tau1; P.s1 = s1;
  P.u1v = u1m; P.v1v = v1m; P.Wfp = Wfpm; P.ufv = ufvm;
  P.H0b = (short*)(ws + OFF_H0B);
  P.H1b = (short*)(ws + OFF_H1B);
  P.St0 = (float*)(ws + OFF_ST0);
  P.St1 = (float*)(ws + OFF_ST1);
  P.flag = (unsigned*)(ws + OFF_FLG);
  P.out = (float*)d_out;

  hipFuncSetAttribute(reinterpret_cast<const void*>(plstm_persist),
                      hipFuncAttributeMaxDynamicSharedMemorySize, SMEM_BYTES);

  prep_weights<<<1536, 256, 0, stream>>>(R0, W1, R1, g0, Wswz);
  prep_vecs<<<8, 256, 0, stream>>>(W1, g0, be0, u1m, v1m);
  prep_head<<<20, 256, 0, stream>>>(Wf, g1, be1, bfv, Wfpm, ufvm);
  hipMemsetAsync(ws + OFF_H0B, 0, ZERO_BYTES, stream);
  plstm_persist<<<NB, NTHR, SMEM_BYTES, stream>>>(P, Wswz);
}

// Round 11
// 7192.598 us; speedup vs baseline: 1.0099x; 1.0099x over previous
//
#include <hip/hip_runtime.h>
#include <hip/hip_bf16.h>

// PhasedLSTM classifier: persistent cooperative kernel.
// 8 groups (32 samples) x 32 slices (16 units) = 256 blocks (1/CU), 8 waves.
// Producer/consumer wave specialization, NO block barriers in the main loop:
//   waves 0-5: MFMA + combine (LDS sub-barrier between), token-gated.
//   wave 6:    polls next round's flags + issues G2L DMA during compute.
//   wave 7:    posts this block's flag as soon as combine stores drain,
//              then stats/x-prefetch for next round + classifier head.
// Exchange semantics: relaxed agent-scope atomics + G2L(aux=16) (proven R9).
// Round r computes L0 step r, L1 step r-1, head step r-2.

#define NB 256
#define NTHR 512
#define T_STEPS 500
#define RON 0.05f
#define ALPHA_LEAK 1e-3f

typedef short short8 __attribute__((ext_vector_type(8)));
typedef float f32x4 __attribute__((ext_vector_type(4)));
typedef unsigned long long ull;

// ---------------- ws layout (bytes) ----------------
#define OFF_WSWZ 0u              // 6291456  swizzled bf16 weights
#define OFF_U1   6291456u        // 8192
#define OFF_V1   6299648u        // 8192
#define OFF_WFP  6307840u        // 20480    Wf' permuted [kk][c][lane] f32
#define OFF_UFV  6328320u        // 128
#define OFF_H0B  6328448u        // 524288   [2][8][16384] bf16, frag order
#define OFF_H1B  6852736u        // 524288
#define OFF_ST0  7377024u        // 131072   [2][8][32 m][32 sl][2] f32
#define OFF_ST1  7508096u        // 131072
#define OFF_FLG0 7639168u        // 1024     [8][32] u32 round flags
#define OFF_FLG1 7640192u        // 1024     (unused, zeroed)
#define ZERO_BYTES 1312768u

// ---------------- LDS layout (bytes) ----------------
// 0      h0b            32768
// 32768  h1bL[2]        65536
// 98304  zbv            25728   (3 x [32][67] f32)
// 124032 musL[2][128]    1024   (mu0,rs0,mu1,rs1 x32 per slot)
// 125056 xtbL[2][160]    1280   (xt[32][4] + xt1[32] per slot)
// 126336 prm             2048
// 128384 wfl            20480   ([kk][c][64] f32)
// 148864 ufl              128
// 148992 tok[8]            32   (barc,arrc,tokf,tokd,toks)
#define SMEM_BYTES 149504

#define AT_LD(p)    __hip_atomic_load((p), __ATOMIC_RELAXED, __HIP_MEMORY_SCOPE_AGENT)
#define AT_ST(p, v) __hip_atomic_store((p), (v), __ATOMIC_RELAXED, __HIP_MEMORY_SCOPE_AGENT)
#define LDS_ADD(p)  __hip_atomic_fetch_add((p), 1u, __ATOMIC_RELEASE, __HIP_MEMORY_SCOPE_WORKGROUP)
#define LDS_LD(p)   __hip_atomic_load((p), __ATOMIC_ACQUIRE, __HIP_MEMORY_SCOPE_WORKGROUP)
#define LDS_ST(p,v) __hip_atomic_store((p), (v), __ATOMIC_RELEASE, __HIP_MEMORY_SCOPE_WORKGROUP)

#define G2L(gp, lp) \
  __builtin_amdgcn_global_load_lds( \
      (const __attribute__((address_space(1))) void*)(gp), \
      (__attribute__((address_space(3))) void*)(lp), 16, 0, 16)

__device__ __forceinline__ short f2bf(float x) {
  unsigned u = __float_as_uint(x);
  unsigned r = (u + 0x7fffu + ((u >> 16) & 1u)) >> 16;
  return (short)r;
}
__device__ __forceinline__ float bf2f(short s) {
  return __uint_as_float(((unsigned)(unsigned short)s) << 16);
}
__device__ __forceinline__ float sigm(float x) { return 1.f / (1.f + __expf(-x)); }
__device__ __forceinline__ float tanh_f(float x) {
  float cx = fminf(fmaxf(x, -15.f), 15.f);
  float e = __expf(2.f * cx);
  return (e - 1.f) / (e + 1.f);
}
__device__ __forceinline__ float timegate(float t, float tau, float s) {
  float phi = fmodf(t - s, tau);
  if (phi < 0.f) phi += tau;
  phi /= tau;
  return phi < 0.5f * RON ? (2.f / RON) * phi
       : (phi < RON ? 2.f - (2.f / RON) * phi : ALPHA_LEAK * phi);
}
// element index (shorts) of (sample m<32, unit k) in a [32][512] bf16 buffer
// stored in 16x16x32-MFMA A-fragment order.
__device__ __forceinline__ int fragidx(int m, int k) {
  return ((((k >> 5) * 2 + (m >> 4)) * 64) + (((k >> 3) & 3) * 16) + (m & 15)) * 8 + (k & 7);
}

// ---------------- prep kernels ----------------
__global__ void prep_weights(const float* __restrict__ R0, const float* __restrict__ W1,
                             const float* __restrict__ R1, const float* __restrict__ g0,
                             short* __restrict__ Wswz) {
  int t = blockIdx.x * 256 + threadIdx.x;   // < 393216
  int lane = t & 63; int rest = t >> 6;
  int nf = rest & 1;  rest >>= 1;
  int kb = rest & 15; rest >>= 4;
  int ch = rest & 1;  rest >>= 1;
  int mm = rest % 3;  int slice = rest / 3;
  int c = ch * 32 + nf * 16 + (lane & 15);
  int gate = c >> 4;
  int unit = slice * 16 + (c & 15);
  int gcol = gate * 512 + unit;
  int k0 = kb * 32 + (lane >> 4) * 8;
  const float* src = (mm == 0) ? R0 : (mm == 1 ? W1 : R1);
  short8 o;
  #pragma unroll
  for (int e = 0; e < 8; ++e) {
    float v = src[(size_t)(k0 + e) * 2048 + gcol];
    if (mm == 1) v *= g0[k0 + e];
    o[e] = f2bf(v);
  }
  *(short8*)(Wswz + (size_t)t * 8) = o;
}

__global__ void prep_vecs(const float* __restrict__ W1, const float* __restrict__ g0,
                          const float* __restrict__ be0,
                          float* __restrict__ u1, float* __restrict__ v1) {
  int c = blockIdx.x * 256 + threadIdx.x;  // < 2048
  float su = 0.f, sv = 0.f;
  for (int k = 0; k < 512; ++k) {
    float w = W1[(size_t)k * 2048 + c];
    su += be0[k] * w; sv += g0[k] * w;
  }
  u1[c] = su; v1[c] = sv;
}

__global__ void prep_head(const float* __restrict__ Wf, const float* __restrict__ g1,
                          const float* __restrict__ be1, const float* __restrict__ bfv,
                          float* __restrict__ Wfp, float* __restrict__ ufv) {
  int t = blockIdx.x * 256 + threadIdx.x;
  if (t < 5120) {
    int kk = t / 640, rem = t - kk * 640, c = rem >> 6, l = rem & 63;
    int k = 8 * l + kk;
    Wfp[t] = g1[k] * Wf[k * 10 + c];
  }
  if (t < 10) {
    float su = bfv[t], sv = 0.f;
    for (int k = 0; k < 512; ++k) {
      float w = Wf[k * 10 + t];
      su += be1[k] * w; sv += g1[k] * w;
    }
    ufv[t] = su; ufv[16 + t] = sv;
  }
}

// ---------------- persistent kernel ----------------
struct Ptrs {
  const float *x, *times, *W0, *b0, *tau0, *s0, *b1, *tau1, *s1;
  const float *u1v, *v1v, *Wfp, *ufv;
  short *H0b, *H1b;
  float *St0, *St1;
  unsigned *flag0, *flag1;
  float *out;
};

__launch_bounds__(NTHR, 1)
__global__ void plstm_persist(Ptrs P, const short* __restrict__ Wswz) {
  extern __shared__ char smem[];
  short* h0b  = (short*)smem;
  short* h1bL = (short*)(smem + 32768);
  float* zbv  = (float*)(smem + 98304);
  float* musL = (float*)(smem + 124032);
  float* xtbL = (float*)(smem + 125056);
  float* prm  = (float*)(smem + 126336);
  float* wfl  = (float*)(smem + 128384);
  float* ufl  = (float*)(smem + 148864);
  unsigned* tok = (unsigned*)(smem + 148992);
  // tok[0]=barc  tok[1]=arrc  tok[2]=tokf  tok[3]=tokd  tok[4]=toks

  const int tid = threadIdx.x;
  const int g = blockIdx.x & 7;
  const int slice = blockIdx.x >> 3;
  const int wid = tid >> 6, lane = tid & 63;
  const int mm = wid >> 1, ch = wid & 1;
  const int gm0 = g * 32;

  // ---- one-time LDS init ----
  if (tid < 8) tok[tid] = 0u;
  for (int i = tid; i < 512; i += NTHR) {
    float v;
    if (i < 192)      { int f = i >> 6, c = i & 63; v = P.W0[f * 2048 + ((c >> 4) << 9) + slice * 16 + (c & 15)]; }
    else if (i < 256) { int c = i & 63; v = P.b0[((c >> 4) << 9) + slice * 16 + (c & 15)]; }
    else if (i < 320) { int c = i & 63; int gc = ((c >> 4) << 9) + slice * 16 + (c & 15);
                        v = P.b1[gc] + P.u1v[gc]; }
    else if (i < 384) { int c = i & 63; v = P.v1v[((c >> 4) << 9) + slice * 16 + (c & 15)]; }
    else if (i < 448) v = 0.f;
    else if (i < 464) v = P.tau0[slice * 16 + (i & 15)];
    else if (i < 480) v = P.s0[slice * 16 + (i & 15)];
    else if (i < 496) v = P.tau1[slice * 16 + (i & 15)];
    else              v = P.s1[slice * 16 + (i & 15)];
    prm[i] = v;
  }
  for (int i = tid; i < 5120; i += NTHR) wfl[i] = P.Wfp[i];
  if (tid < 32) ufl[tid] = P.ufv[tid];

  // ---- resident weights for compute waves ----
  short8 wr[16][2];
  if (wid < 6) {
    const short* wb = Wswz + ((((size_t)slice * 3 + mm) * 2 + ch) * 32 * 64) * 8;
    #pragma unroll
    for (int kb = 0; kb < 16; ++kb)
      #pragma unroll
      for (int nf = 0; nf < 2; ++nf) {
        wr[kb][nf] = *(const short8*)(wb + ((kb * 2 + nf) * 64 + lane) * 8);
        asm volatile("" : "+v"(wr[kb][nf]));
      }
  }
  // register-resident recurrent state (fixed item->thread mapping)
  float h0A0 = 0.f, h0A1 = 0.f, c0A0 = 0.f, c0A1 = 0.f;   // tid<256: L0 item tid
  float h1B0 = 0.f, h1B1 = 0.f, c1B0 = 0.f, c1B1 = 0.f;   // tid>=256: L1 item tid-256
  float h1C0 = 0.f, h1C1 = 0.f, c1C0 = 0.f, c1C1 = 0.f;   // tid<128:  L1 item 128+tid
  __syncthreads();   // the ONLY block barrier

  // ================= prologue: prep round 0 =================
  if (wid == 6) {
    const char* gA = (const char*)(P.H0b + ((size_t)1 * 8 + g) * 16384);
    const char* gB = (const char*)(P.H1b + ((size_t)0 * 8 + g) * 16384);
    char* lA = (char*)h0b;
    char* lB = (char*)h1bL;
    #pragma unroll
    for (int j = 0; j < 32; ++j) {
      unsigned off = j * 1024u + (unsigned)lane * 16u;
      G2L(gA + off, lA + off);
      G2L(gB + off, lB + off);
    }
    asm volatile("s_waitcnt vmcnt(0)" ::: "memory");
    if (lane == 0) { LDS_ST(&tok[2], 1u); LDS_ST(&tok[3], 1u); }
  } else if (wid == 7) {
    for (int it_ = 0; it_ < 200000; ++it_) { if (LDS_LD(&tok[2]) >= 1u) break; __builtin_amdgcn_s_sleep(1); }
    {  // stats(0): zeroed St -> mu=0, rs=rsqrt(1e-3)
      const int layer = lane >> 5, m = lane & 31;
      float* mus = musL;   // slot 0
      mus[layer * 64 + m] = 0.f;
      mus[layer * 64 + 32 + m] = rsqrtf(1e-3f);
      // xtb(0)
      float* xt = xtbL;
      if (lane < 32) {
        const float* xp = P.x + ((size_t)(gm0 + lane) * T_STEPS) * 3;
        xt[lane * 4 + 0] = xp[0]; xt[lane * 4 + 1] = xp[1]; xt[lane * 4 + 2] = xp[2];
        xt[lane * 4 + 3] = P.times[(size_t)(gm0 + lane) * T_STEPS];
      } else {
        int m2 = lane - 32;
        xt[128 + m2] = P.times[(size_t)(gm0 + m2) * T_STEPS];
      }
    }
    if (lane == 0) LDS_ST(&tok[4], 1u);
  }

  // ================= main loop =================
  for (int r = 0; r <= T_STEPS + 1; ++r) {
    if (wid < 6) {
      // ---- gate: DMA(r) + stats(r) done ----
      { const unsigned tgt = (unsigned)(r + 1);
        for (int it_ = 0; it_ < 400000; ++it_) {
          if (LDS_LD(&tok[3]) >= tgt && LDS_LD(&tok[4]) >= tgt) break;
          __builtin_amdgcn_s_sleep(1);
        } }
      // ---- MFMA ----
      if (r <= T_STEPS) {
        f32x4 acc[2][2] = {};
        const short* asrc = (mm == 2) ? (h1bL + (r & 1) * 16384) : h0b;
        #pragma unroll
        for (int kb = 0; kb < 16; ++kb) {
          short8 a0 = *(const short8*)(asrc + ((kb * 2 + 0) * 64 + lane) * 8);
          short8 a1 = *(const short8*)(asrc + ((kb * 2 + 1) * 64 + lane) * 8);
          #pragma unroll
          for (int nf = 0; nf < 2; ++nf) {
            acc[0][nf] = __builtin_amdgcn_mfma_f32_16x16x32_bf16(a0, wr[kb][nf], acc[0][nf], 0, 0, 0);
            acc[1][nf] = __builtin_amdgcn_mfma_f32_16x16x32_bf16(a1, wr[kb][nf], acc[1][nf], 0, 0, 0);
          }
        }
        float* z = zbv + mm * 2144;
        #pragma unroll
        for (int mf = 0; mf < 2; ++mf)
          #pragma unroll
          for (int nf = 0; nf < 2; ++nf)
            #pragma unroll
            for (int q = 0; q < 4; ++q) {
              int row = mf * 16 + (lane >> 4) * 4 + q;
              int col = ch * 32 + nf * 16 + (lane & 15);
              z[row * 67 + col] = acc[mf][nf][q];
            }
      }
      // ---- sub-barrier among waves 0-5 (zbv ready) ----
      if (lane == 0) LDS_ADD(&tok[0]);
      { const unsigned tgt = 6u * (unsigned)(r + 1);
        for (int it_ = 0; it_ < (1 << 22); ++it_) { if (LDS_LD(&tok[0]) >= tgt) break; } }
      // ---- combine ----
      const bool l0act = (r < T_STEPS);
      const bool l1act = (r >= 1 && r <= T_STEPS);
      const float* xt = xtbL + (r & 1) * 160;
      const float* mus = musL + (r & 1) * 128;
      if (tid < 256 && l0act) {          // L0 item tid
        int m = tid >> 3, u0 = (tid & 7) << 1;
        float x0 = xt[m * 4], x1 = xt[m * 4 + 1], x2 = xt[m * 4 + 2], tmv = xt[m * 4 + 3];
        unsigned pack = 0; float hnv[2];
        #pragma unroll
        for (int uu = 0; uu < 2; ++uu) {
          int u = u0 + uu;
          float zg[4];
          #pragma unroll
          for (int q = 0; q < 4; ++q) {
            int c = q * 16 + u;
            zg[q] = zbv[m * 67 + c] + prm[192 + c]
                  + x0 * prm[c] + x1 * prm[64 + c] + x2 * prm[128 + c];
          }
          float iv = sigm(zg[0]), fv = sigm(zg[1]), gv = tanh_f(zg[2]), ov = sigm(zg[3]);
          float cold = uu ? c0A1 : c0A0, hold = uu ? h0A1 : h0A0;
          float cp = fv * cold + iv * gv;
          float hp = ov * tanh_f(cp);
          float k = timegate(tmv, prm[448 + u], prm[464 + u]);
          float hn = k * hp + (1.f - k) * hold;
          float cn = k * cp + (1.f - k) * cold;
          if (uu) { h0A1 = hn; c0A1 = cn; } else { h0A0 = hn; c0A0 = cn; }
          hnv[uu] = hn;
          pack |= ((unsigned)(unsigned short)f2bf(hn)) << (16 * uu);
        }
        AT_ST((unsigned*)(P.H0b + ((size_t)(r & 1) * 8 + g) * 16384 + fragidx(m, slice * 16 + u0)), pack);
        float sr = hnv[0] + hnv[1], qr = hnv[0] * hnv[0] + hnv[1] * hnv[1];
        sr += __shfl_down(sr, 4, 8); qr += __shfl_down(qr, 4, 8);
        sr += __shfl_down(sr, 2, 8); qr += __shfl_down(qr, 2, 8);
        sr += __shfl_down(sr, 1, 8); qr += __shfl_down(qr, 1, 8);
        if ((tid & 7) == 0) {
          ull pv = ((ull)__float_as_uint(qr) << 32) | __float_as_uint(sr);
          AT_ST((ull*)(P.St0 + ((size_t)(r & 1) * 8 + g) * 2048) + m * 32 + slice, pv);
        }
      }
      #pragma unroll
      for (int pass = 0; pass < 2; ++pass) {   // L1: 256 items on 384 threads
        int idx = -1;
        if (pass == 0 && tid >= 256) idx = tid - 256;
        if (pass == 1 && tid < 128)  idx = 128 + tid;
        if (idx >= 0 && l1act) {
          int m = idx >> 3, u0 = (idx & 7) << 1;
          float mu0m = mus[m], rs0m = mus[32 + m];
          float tmv = xt[128 + m];
          unsigned pack = 0; float hnv[2];
          #pragma unroll
          for (int uu = 0; uu < 2; ++uu) {
            int u = u0 + uu;
            float zg[4];
            #pragma unroll
            for (int q = 0; q < 4; ++q) {
              int c = q * 16 + u;
              float zA = zbv[2144 + m * 67 + c];
              float zB = zbv[4288 + m * 67 + c];
              zg[q] = rs0m * zA + zB + prm[256 + c] - mu0m * rs0m * prm[320 + c];
            }
            float iv = sigm(zg[0]), fv = sigm(zg[1]), gv = tanh_f(zg[2]), ov = sigm(zg[3]);
            float cold, hold;
            if (pass == 0) { cold = uu ? c1B1 : c1B0; hold = uu ? h1B1 : h1B0; }
            else           { cold = uu ? c1C1 : c1C0; hold = uu ? h1C1 : h1C0; }
            float cp = fv * cold + iv * gv;
            float hp = ov * tanh_f(cp);
            float k = timegate(tmv, prm[480 + u], prm[496 + u]);
            float hn = k * hp + (1.f - k) * hold;
            float cn = k * cp + (1.f - k) * cold;
            if (pass == 0) { if (uu) { h1B1 = hn; c1B1 = cn; } else { h1B0 = hn; c1B0 = cn; } }
            else           { if (uu) { h1C1 = hn; c1C1 = cn; } else { h1C0 = hn; c1C0 = cn; } }
            hnv[uu] = hn;
            pack |= ((unsigned)(unsigned short)f2bf(hn)) << (16 * uu);
          }
          AT_ST((unsigned*)(P.H1b + ((size_t)((r + 1) & 1) * 8 + g) * 16384 + fragidx(m, slice * 16 + u0)), pack);
          float sr = hnv[0] + hnv[1], qr = hnv[0] * hnv[0] + hnv[1] * hnv[1];
          sr += __shfl_down(sr, 4, 8); qr += __shfl_down(qr, 4, 8);
          sr += __shfl_down(sr, 2, 8); qr += __shfl_down(qr, 2, 8);
          sr += __shfl_down(sr, 1, 8); qr += __shfl_down(qr, 1, 8);
          if ((idx & 7) == 0) {
            ull pv = ((ull)__float_as_uint(qr) << 32) | __float_as_uint(sr);
            AT_ST((ull*)(P.St1 + ((size_t)((r + 1) & 1) * 8 + g) * 2048) + m * 32 + slice, pv);
          }
        }
      }
      // ---- drain own stores, signal arrival ----
      asm volatile("s_waitcnt vmcnt(0)" ::: "memory");
      if (lane == 0) LDS_ADD(&tok[1]);
    } else if (wid == 6) {
      // ---- stager: prep round r+1 while compute does round r ----
      const int rr = r + 1;
      if (rr <= T_STEPS + 1) {
        const unsigned tgt = (unsigned)rr;
        const unsigned* fp = P.flag0 + g * 32 + (lane & 31);
        for (int it_ = 0; it_ < 400000; ++it_) {
          unsigned v = (lane < 32) ? AT_LD(fp) : 0xFFFFFFFFu;
          if (__all((int)(v >= tgt))) break;
          __builtin_amdgcn_s_sleep(1);
        }
        if (lane == 0) LDS_ST(&tok[2], (unsigned)(rr + 1));
        const char* gA = (const char*)(P.H0b + ((size_t)((rr + 1) & 1) * 8 + g) * 16384);
        const char* gB = (const char*)(P.H1b + ((size_t)(rr & 1) * 8 + g) * 16384);
        char* lA = (char*)h0b;
        char* lB = (char*)(h1bL + (rr & 1) * 16384);
        #pragma unroll
        for (int j = 0; j < 32; ++j) {
          unsigned off = j * 1024u + (unsigned)lane * 16u;
          G2L(gA + off, lA + off);
          G2L(gB + off, lB + off);
        }
        asm volatile("s_waitcnt vmcnt(0)" ::: "memory");
        if (lane == 0) LDS_ST(&tok[3], (unsigned)(rr + 1));
      }
    } else {
      // ---- finisher: post flag ASAP, then stats/xtb for r+1, then head(r) ----
      { const unsigned tgt = 6u * (unsigned)(r + 1);
        for (int it_ = 0; it_ < 400000; ++it_) {
          if (LDS_LD(&tok[1]) >= tgt) break;
          __builtin_amdgcn_s_sleep(1);
        } }
      if (lane == 0) AT_ST(P.flag0 + g * 32 + slice, (unsigned)(r + 1));
      const int rr = r + 1;
      if (rr <= T_STEPS + 1) {
        { const unsigned tgt = (unsigned)(rr + 1);
          for (int it_ = 0; it_ < 400000; ++it_) {
            if (LDS_LD(&tok[2]) >= tgt) break;
            __builtin_amdgcn_s_sleep(1);
          } }
        // stats(rr)
        const int layer = lane >> 5, m = lane & 31;
        const float* base = layer
            ? (P.St1 + ((size_t)(rr & 1) * 8 + g) * 2048 + m * 64)
            : (P.St0 + ((size_t)((rr + 1) & 1) * 8 + g) * 2048 + m * 64);
        const ull* bu = (const ull*)base;
        float s_ = 0.f, q_ = 0.f;
        #pragma unroll
        for (int sl = 0; sl < 32; ++sl) {
          ull v = AT_LD(bu + sl);
          s_ += __uint_as_float((unsigned)v);
          q_ += __uint_as_float((unsigned)(v >> 32));
        }
        float mu = s_ * (1.f / 512.f);
        float var = q_ * (1.f / 512.f) - mu * mu;
        float* mus = musL + (rr & 1) * 128;
        mus[layer * 64 + m] = mu;
        mus[layer * 64 + 32 + m] = rsqrtf(var + 1e-3f);
        // xtb(rr)
        float* xt = xtbL + (rr & 1) * 160;
        if (lane < 32) {
          int step = (rr < T_STEPS) ? rr : (T_STEPS - 1);
          const float* xp = P.x + ((size_t)(gm0 + lane) * T_STEPS + step) * 3;
          xt[lane * 4 + 0] = xp[0]; xt[lane * 4 + 1] = xp[1]; xt[lane * 4 + 2] = xp[2];
          xt[lane * 4 + 3] = P.times[(size_t)(gm0 + lane) * T_STEPS + step];
        } else {
          int m2 = lane - 32;
          int s1_ = (rr >= 1) ? rr - 1 : 0;
          if (s1_ > T_STEPS - 1) s1_ = T_STEPS - 1;
          xt[128 + m2] = P.times[(size_t)(gm0 + m2) * T_STEPS + s1_];
        }
        if (lane == 0) LDS_ST(&tok[4], (unsigned)(rr + 1));
      }
      // head(r): output step r-2
      if (r >= 2) {
        const int msam = slice;
        const short* h1r = h1bL + (r & 1) * 16384;
        short8 hv8 = *(const short8*)(h1r + fragidx(msam, lane * 8));
        float lg[10];
        #pragma unroll
        for (int c = 0; c < 10; ++c) lg[c] = 0.f;
        #pragma unroll
        for (int kk = 0; kk < 8; ++kk) {
          float hv = bf2f(hv8[kk]);
          const float* wf = wfl + kk * 640 + lane;
          #pragma unroll
          for (int c = 0; c < 10; ++c) lg[c] += hv * wf[c * 64];
        }
        #pragma unroll
        for (int off = 32; off > 0; off >>= 1)
          #pragma unroll
          for (int c = 0; c < 10; ++c) lg[c] += __shfl_down(lg[c], off, 64);
        if (lane == 0) {
          const float* mus = musL + (r & 1) * 128;
          float m1 = mus[64 + msam], r1 = mus[96 + msam];
          float logit[10], mx = -1e30f;
          #pragma unroll
          for (int c = 0; c < 10; ++c) {
            logit[c] = r1 * lg[c] + ufl[c] - m1 * r1 * ufl[16 + c];
            mx = fmaxf(mx, logit[c]);
          }
          float ssum = 0.f;
          #pragma unroll
          for (int c = 0; c < 10; ++c) { logit[c] = expf(logit[c] - mx); ssum += logit[c]; }
          float inv = 1.f / ssum;
          float* op = P.out + ((size_t)(gm0 + msam) * T_STEPS + (r - 2)) * 10;
          #pragma unroll
          for (int c = 0; c < 10; ++c) op[c] = logit[c] * inv;
        }
      }
    }
  }
}

extern "C" void kernel_launch(void* const* d_in, const int* in_sizes, int n_in,
                              void* d_out, int out_size, void* d_ws, size_t ws_size,
                              hipStream_t stream) {
  const float* x    = (const float*)d_in[0];
  const float* tms  = (const float*)d_in[1];
  const float* W0   = (const float*)d_in[2];
  const float* R0   = (const float*)d_in[3];
  const float* b0   = (const float*)d_in[4];
  const float* tau0 = (const float*)d_in[5];
  const float* s0   = (const float*)d_in[6];
  const float* g0   = (const float*)d_in[7];
  const float* be0  = (const float*)d_in[8];
  const float* W1   = (const float*)d_in[9];
  const float* R1   = (const float*)d_in[10];
  const float* b1   = (const float*)d_in[11];
  const float* tau1 = (const float*)d_in[12];
  const float* s1   = (const float*)d_in[13];
  const float* g1   = (const float*)d_in[14];
  const float* be1  = (const float*)d_in[15];
  const float* Wf   = (const float*)d_in[16];
  const float* bfv  = (const float*)d_in[17];

  char* ws = (char*)d_ws;
  short* Wswz = (short*)(ws + OFF_WSWZ);
  float* u1m  = (float*)(ws + OFF_U1);
  float* v1m  = (float*)(ws + OFF_V1);
  float* Wfpm = (float*)(ws + OFF_WFP);
  float* ufvm = (float*)(ws + OFF_UFV);

  Ptrs P;
  P.x = x; P.times = tms; P.W0 = W0; P.b0 = b0; P.tau0 = tau0; P.s0 = s0;
  P.b1 = b1; P.tau1 = tau1; P.s1 = s1;
  P.u1v = u1m; P.v1v = v1m; P.Wfp = Wfpm; P.ufv = ufvm;
  P.H0b = (short*)(ws + OFF_H0B);
  P.H1b = (short*)(ws + OFF_H1B);
  P.St0 = (float*)(ws + OFF_ST0);
  P.St1 = (float*)(ws + OFF_ST1);
  P.flag0 = (unsigned*)(ws + OFF_FLG0);
  P.flag1 = (unsigned*)(ws + OFF_FLG1);
  P.out = (float*)d_out;

  hipFuncSetAttribute(reinterpret_cast<const void*>(plstm_persist),
                      hipFuncAttributeMaxDynamicSharedMemorySize, SMEM_BYTES);

  prep_weights<<<1536, 256, 0, stream>>>(R0, W1, R1, g0, Wswz);
  prep_vecs<<<8, 256, 0, stream>>>(W1, g0, be0, u1m, v1m);
  prep_head<<<20, 256, 0, stream>>>(Wf, g1, be1, bfv, Wfpm, ufvm);
  hipMemsetAsync(ws + OFF_H0B, 0, ZERO_BYTES, stream);
  plstm_persist<<<NB, NTHR, SMEM_BYTES, stream>>>(P, Wswz);
}

// Round 12
// 5899.912 us; speedup vs baseline: 1.2312x; 1.2191x over previous
//
#include <hip/hip_runtime.h>
#include <hip/hip_bf16.h>

// PhasedLSTM classifier: persistent cooperative kernel (R9 skeleton, tightened).
// 8 groups (32 samples) x 32 slices (16 units) = 256 blocks (1/CU), 8 waves.
// Per round: wave0 {poll flags -> issue ALL 64KB G2L DMA}; wave6 {poll -> LN
// stats}; wave7 {x/t prefetch}; stage-bar; MFMA (waves0-5); z-bar; combine
// (512 thr 1:1, register h/c state); combine-bar; flag post + head (wave7).
// 3 block barriers/round. Exchange: relaxed agent-scope atomics + G2L(aux=16).
// Round r computes L0 step r, L1 step r-1, head step r-2.

#define NB 256
#define NTHR 512
#define T_STEPS 500
#define RON 0.05f
#define ALPHA_LEAK 1e-3f

typedef short short8 __attribute__((ext_vector_type(8)));
typedef float f32x4 __attribute__((ext_vector_type(4)));
typedef unsigned long long ull;

// ---------------- ws layout (bytes) ----------------
#define OFF_WSWZ 0u              // 6291456  swizzled bf16 weights
#define OFF_U1   6291456u        // 8192
#define OFF_V1   6299648u        // 8192
#define OFF_WFP  6307840u        // 20480    Wf' permuted [kk][c][lane] f32
#define OFF_UFV  6328320u        // 128
#define OFF_H0B  6328448u        // 524288   [2][8][16384] bf16, frag order
#define OFF_H1B  6852736u        // 524288
#define OFF_ST0  7377024u        // 131072   [2][8][32 m][32 sl][2] f32
#define OFF_ST1  7508096u        // 131072
#define OFF_FLG0 7639168u        // 1024     [8][32] u32 round flags
#define OFF_FLG1 7640192u        // 1024     (unused, zeroed)
#define ZERO_BYTES 1312768u

// ---------------- LDS layout (bytes) ----------------
// 0      h0b            32768
// 32768  h1bL[2]        65536
// 98304  zbv            25728   (3 x [32][67] f32)
// 124032 mus              512   (mu0,rs0,mu1,rs1 x 32)
// 124544 xtb              640   (x0..x2,t x32 + t1 x32)
// 125184 prm             2048
// 127232 wfl            20480   ([kk][c][64] f32, conflict-free)
// 147712 ufl              128
#define SMEM_BYTES 147968

#define AT_LD(p)    __hip_atomic_load((p), __ATOMIC_RELAXED, __HIP_MEMORY_SCOPE_AGENT)
#define AT_ST(p, v) __hip_atomic_store((p), (v), __ATOMIC_RELAXED, __HIP_MEMORY_SCOPE_AGENT)

#define G2L(gp, lp) \
  __builtin_amdgcn_global_load_lds( \
      (const __attribute__((address_space(1))) void*)(gp), \
      (__attribute__((address_space(3))) void*)(lp), 16, 0, 16)

__device__ __forceinline__ short f2bf(float x) {
  unsigned u = __float_as_uint(x);
  unsigned r = (u + 0x7fffu + ((u >> 16) & 1u)) >> 16;
  return (short)r;
}
__device__ __forceinline__ float bf2f(short s) {
  return __uint_as_float(((unsigned)(unsigned short)s) << 16);
}
__device__ __forceinline__ float sigm(float x) { return 1.f / (1.f + __expf(-x)); }
__device__ __forceinline__ float tanh_f(float x) {
  float cx = fminf(fmaxf(x, -15.f), 15.f);
  float e = __expf(2.f * cx);
  return (e - 1.f) / (e + 1.f);
}
__device__ __forceinline__ float timegate(float t, float tau, float s) {
  float phi = fmodf(t - s, tau);
  if (phi < 0.f) phi += tau;
  phi /= tau;
  return phi < 0.5f * RON ? (2.f / RON) * phi
       : (phi < RON ? 2.f - (2.f / RON) * phi : ALPHA_LEAK * phi);
}
// element index (shorts) of (sample m<32, unit k) in a [32][512] bf16 buffer
// stored in 16x16x32-MFMA A-fragment order.
__device__ __forceinline__ int fragidx(int m, int k) {
  return ((((k >> 5) * 2 + (m >> 4)) * 64) + (((k >> 3) & 3) * 16) + (m & 15)) * 8 + (k & 7);
}

// ---------------- prep kernels ----------------
__global__ void prep_weights(const float* __restrict__ R0, const float* __restrict__ W1,
                             const float* __restrict__ R1, const float* __restrict__ g0,
                             short* __restrict__ Wswz) {
  int t = blockIdx.x * 256 + threadIdx.x;   // < 393216
  int lane = t & 63; int rest = t >> 6;
  int nf = rest & 1;  rest >>= 1;
  int kb = rest & 15; rest >>= 4;
  int ch = rest & 1;  rest >>= 1;
  int mm = rest % 3;  int slice = rest / 3;
  int c = ch * 32 + nf * 16 + (lane & 15);
  int gate = c >> 4;
  int unit = slice * 16 + (c & 15);
  int gcol = gate * 512 + unit;
  int k0 = kb * 32 + (lane >> 4) * 8;
  const float* src = (mm == 0) ? R0 : (mm == 1 ? W1 : R1);
  short8 o;
  #pragma unroll
  for (int e = 0; e < 8; ++e) {
    float v = src[(size_t)(k0 + e) * 2048 + gcol];
    if (mm == 1) v *= g0[k0 + e];
    o[e] = f2bf(v);
  }
  *(short8*)(Wswz + (size_t)t * 8) = o;
}

__global__ void prep_vecs(const float* __restrict__ W1, const float* __restrict__ g0,
                          const float* __restrict__ be0,
                          float* __restrict__ u1, float* __restrict__ v1) {
  int c = blockIdx.x * 256 + threadIdx.x;  // < 2048
  float su = 0.f, sv = 0.f;
  for (int k = 0; k < 512; ++k) {
    float w = W1[(size_t)k * 2048 + c];
    su += be0[k] * w; sv += g0[k] * w;
  }
  u1[c] = su; v1[c] = sv;
}

__global__ void prep_head(const float* __restrict__ Wf, const float* __restrict__ g1,
                          const float* __restrict__ be1, const float* __restrict__ bfv,
                          float* __restrict__ Wfp, float* __restrict__ ufv) {
  int t = blockIdx.x * 256 + threadIdx.x;
  if (t < 5120) {
    int kk = t / 640, rem = t - kk * 640, c = rem >> 6, l = rem & 63;
    int k = 8 * l + kk;
    Wfp[t] = g1[k] * Wf[k * 10 + c];
  }
  if (t < 10) {
    float su = bfv[t], sv = 0.f;
    for (int k = 0; k < 512; ++k) {
      float w = Wf[k * 10 + t];
      su += be1[k] * w; sv += g1[k] * w;
    }
    ufv[t] = su; ufv[16 + t] = sv;
  }
}

// ---------------- persistent kernel ----------------
struct Ptrs {
  const float *x, *times, *W0, *b0, *tau0, *s0, *b1, *tau1, *s1;
  const float *u1v, *v1v, *Wfp, *ufv;
  short *H0b, *H1b;
  float *St0, *St1;
  unsigned *flag0, *flag1;
  float *out;
};

__launch_bounds__(NTHR, 1)
__global__ void plstm_persist(Ptrs P, const short* __restrict__ Wswz) {
  extern __shared__ char smem[];
  short* h0b  = (short*)smem;
  short* h1bL = (short*)(smem + 32768);
  float* zbv  = (float*)(smem + 98304);
  float* mus  = (float*)(smem + 124032);
  float* xtb  = (float*)(smem + 124544);
  float* prm  = (float*)(smem + 125184);
  float* wfl  = (float*)(smem + 127232);
  float* ufl  = (float*)(smem + 147712);

  const int tid = threadIdx.x;
  const int g = blockIdx.x & 7;
  const int slice = blockIdx.x >> 3;
  const int wid = tid >> 6, lane = tid & 63;
  const int mm = wid >> 1, ch = wid & 1;
  const int gm0 = g * 32;

  // ---- one-time LDS init: params + head weights ----
  for (int i = tid; i < 512; i += NTHR) {
    float v;
    if (i < 192)      { int f = i >> 6, c = i & 63; v = P.W0[f * 2048 + ((c >> 4) << 9) + slice * 16 + (c & 15)]; }
    else if (i < 256) { int c = i & 63; v = P.b0[((c >> 4) << 9) + slice * 16 + (c & 15)]; }
    else if (i < 320) { int c = i & 63; int gc = ((c >> 4) << 9) + slice * 16 + (c & 15);
                        v = P.b1[gc] + P.u1v[gc]; }
    else if (i < 384) { int c = i & 63; v = P.v1v[((c >> 4) << 9) + slice * 16 + (c & 15)]; }
    else if (i < 448) v = 0.f;
    else if (i < 464) v = P.tau0[slice * 16 + (i & 15)];
    else if (i < 480) v = P.s0[slice * 16 + (i & 15)];
    else if (i < 496) v = P.tau1[slice * 16 + (i & 15)];
    else              v = P.s1[slice * 16 + (i & 15)];
    prm[i] = v;
  }
  for (int i = tid; i < 5120; i += NTHR) wfl[i] = P.Wfp[i];
  if (tid < 32) ufl[tid] = P.ufv[tid];

  // ---- resident weights (waves 0-5): 128 VGPRs ----
  short8 wr[16][2];
  if (wid < 6) {
    const short* wb = Wswz + ((((size_t)slice * 3 + mm) * 2 + ch) * 32 * 64) * 8;
    #pragma unroll
    for (int kb = 0; kb < 16; ++kb)
      #pragma unroll
      for (int nf = 0; nf < 2; ++nf) {
        wr[kb][nf] = *(const short8*)(wb + ((kb * 2 + nf) * 64 + lane) * 8);
        asm volatile("" : "+v"(wr[kb][nf]));
      }
  }
  // register-resident recurrent state: thread owns 2 units of one item
  // tid<256: L0 item tid; tid>=256: L1 item tid-256
  float hS0 = 0.f, hS1 = 0.f, cS0 = 0.f, cS1 = 0.f;
  __syncthreads();

  for (int r = 0; r <= T_STEPS + 1; ++r) {
    const int bufA = (r + 1) & 1;
    const int bufB = r & 1;
    short* h1s = h1bL + bufB * 16384;

    // ---- pre-stage (no barrier before): per-wave roles ----
    if (wid == 0) {
      // poll flags, then issue ALL DMA from this wave (no VGPR round-trip)
      { const unsigned tgt = (unsigned)r;
        const unsigned* fp = P.flag0 + g * 32 + (lane & 31);
        for (int it_ = 0; it_ < 200000; ++it_) {
          unsigned v = (lane < 32) ? AT_LD(fp) : 0xFFFFFFFFu;
          if (__all((int)(v >= tgt))) break;
          __builtin_amdgcn_s_sleep(1);
        } }
      const char* gA = (const char*)(P.H0b + ((size_t)bufA * 8 + g) * 16384);
      const char* gB = (const char*)(P.H1b + ((size_t)bufB * 8 + g) * 16384);
      char* lA = (char*)h0b;
      char* lB = (char*)h1s;
      #pragma unroll
      for (int j = 0; j < 32; ++j) {
        unsigned off = j * 1024u + (unsigned)lane * 16u;
        G2L(gA + off, lA + off);
        G2L(gB + off, lB + off);
      }
    } else if (wid == 6) {
      // independent poll, then LN stats for both layers
      { const unsigned tgt = (unsigned)r;
        const unsigned* fp = P.flag0 + g * 32 + (lane & 31);
        for (int it_ = 0; it_ < 200000; ++it_) {
          unsigned v = (lane < 32) ? AT_LD(fp) : 0xFFFFFFFFu;
          if (__all((int)(v >= tgt))) break;
          __builtin_amdgcn_s_sleep(1);
        } }
      const int layer = lane >> 5, m = lane & 31;
      const float* base = layer ? (P.St1 + ((size_t)bufB * 8 + g) * 2048 + m * 64)
                                : (P.St0 + ((size_t)bufA * 8 + g) * 2048 + m * 64);
      const ull* bu = (const ull*)base;
      float s_ = 0.f, q_ = 0.f;
      #pragma unroll
      for (int sl = 0; sl < 32; ++sl) {
        ull v = AT_LD(bu + sl);
        s_ += __uint_as_float((unsigned)v);
        q_ += __uint_as_float((unsigned)(v >> 32));
      }
      float mu = s_ * (1.f / 512.f);
      float var = q_ * (1.f / 512.f) - mu * mu;
      mus[layer * 64 + m] = mu;
      mus[layer * 64 + 32 + m] = rsqrtf(var + 1e-3f);
    } else if (wid == 7) {
      // x/times prefetch (pure inputs, no ordering needed)
      int m = lane & 31;
      if (lane < 32) {
        int step = (r < T_STEPS) ? r : (T_STEPS - 1);
        const float* xp = P.x + ((size_t)(gm0 + m) * T_STEPS + step) * 3;
        xtb[m * 4 + 0] = xp[0]; xtb[m * 4 + 1] = xp[1]; xtb[m * 4 + 2] = xp[2];
        xtb[m * 4 + 3] = P.times[(size_t)(gm0 + m) * T_STEPS + step];
      } else {
        int s1_ = (r >= 1) ? r - 1 : 0;
        if (s1_ > T_STEPS - 1) s1_ = T_STEPS - 1;
        xtb[128 + m] = P.times[(size_t)(gm0 + m) * T_STEPS + s1_];
      }
    }
    __syncthreads();                     // stage-bar: DMA drained, stats ready
    float m1r = 0.f, r1r = 0.f;
    if (wid == 7) { m1r = mus[64 + slice]; r1r = mus[96 + slice]; }  // hoist

    // ---- MFMA: z-slice = A @ Wslice (waves 0-5) ----
    if (wid < 6 && r <= T_STEPS) {
      f32x4 acc[2][2] = {};
      const short* asrc = (mm == 2) ? h1s : h0b;
      #pragma unroll
      for (int kb = 0; kb < 16; ++kb) {
        short8 a0 = *(const short8*)(asrc + ((kb * 2 + 0) * 64 + lane) * 8);
        short8 a1 = *(const short8*)(asrc + ((kb * 2 + 1) * 64 + lane) * 8);
        #pragma unroll
        for (int nf = 0; nf < 2; ++nf) {
          acc[0][nf] = __builtin_amdgcn_mfma_f32_16x16x32_bf16(a0, wr[kb][nf], acc[0][nf], 0, 0, 0);
          acc[1][nf] = __builtin_amdgcn_mfma_f32_16x16x32_bf16(a1, wr[kb][nf], acc[1][nf], 0, 0, 0);
        }
      }
      float* z = zbv + mm * 2144;
      #pragma unroll
      for (int mf = 0; mf < 2; ++mf)
        #pragma unroll
        for (int nf = 0; nf < 2; ++nf)
          #pragma unroll
          for (int q = 0; q < 4; ++q) {
            int row = mf * 16 + (lane >> 4) * 4 + q;
            int col = ch * 32 + nf * 16 + (lane & 15);
            z[row * 67 + col] = acc[mf][nf][q];
          }
    }
    __syncthreads();                     // z-bar

    // ---- combine: 1:1 thread->item, register state ----
    {
      const bool isL0 = (tid < 256);
      const bool act = isL0 ? (r < T_STEPS) : (r >= 1 && r <= T_STEPS);
      if (act) {
        const int idx = isL0 ? tid : (tid - 256);
        const int m = idx >> 3, u0 = (idx & 7) << 1;
        unsigned pack = 0; float hnv[2];
        if (isL0) {
          float x0 = xtb[m * 4], x1 = xtb[m * 4 + 1], x2 = xtb[m * 4 + 2];
          float tmv = xtb[m * 4 + 3];
          #pragma unroll
          for (int uu = 0; uu < 2; ++uu) {
            int u = u0 + uu;
            float zg[4];
            #pragma unroll
            for (int q = 0; q < 4; ++q) {
              int c = q * 16 + u;
              zg[q] = zbv[m * 67 + c] + prm[192 + c]
                    + x0 * prm[c] + x1 * prm[64 + c] + x2 * prm[128 + c];
            }
            float iv = sigm(zg[0]), fv = sigm(zg[1]), gv = tanh_f(zg[2]), ov = sigm(zg[3]);
            float cold = uu ? cS1 : cS0, hold = uu ? hS1 : hS0;
            float cp = fv * cold + iv * gv;
            float hp = ov * tanh_f(cp);
            float k = timegate(tmv, prm[448 + u], prm[464 + u]);
            float hn = k * hp + (1.f - k) * hold;
            float cn = k * cp + (1.f - k) * cold;
            if (uu) { hS1 = hn; cS1 = cn; } else { hS0 = hn; cS0 = cn; }
            hnv[uu] = hn;
            pack |= ((unsigned)(unsigned short)f2bf(hn)) << (16 * uu);
          }
          AT_ST((unsigned*)(P.H0b + ((size_t)bufB * 8 + g) * 16384 + fragidx(m, slice * 16 + u0)), pack);
        } else {
          float mu0m = mus[m], rs0m = mus[32 + m];
          float tmv = xtb[128 + m];
          #pragma unroll
          for (int uu = 0; uu < 2; ++uu) {
            int u = u0 + uu;
            float zg[4];
            #pragma unroll
            for (int q = 0; q < 4; ++q) {
              int c = q * 16 + u;
              float zA = zbv[2144 + m * 67 + c];   // h0 @ (g0.W1)
              float zB = zbv[4288 + m * 67 + c];   // h1 @ R1
              zg[q] = rs0m * zA + zB + prm[256 + c] - mu0m * rs0m * prm[320 + c];
            }
            float iv = sigm(zg[0]), fv = sigm(zg[1]), gv = tanh_f(zg[2]), ov = sigm(zg[3]);
            float cold = uu ? cS1 : cS0, hold = uu ? hS1 : hS0;
            float cp = fv * cold + iv * gv;
            float hp = ov * tanh_f(cp);
            float k = timegate(tmv, prm[480 + u], prm[496 + u]);
            float hn = k * hp + (1.f - k) * hold;
            float cn = k * cp + (1.f - k) * cold;
            if (uu) { hS1 = hn; cS1 = cn; } else { hS0 = hn; cS0 = cn; }
            hnv[uu] = hn;
            pack |= ((unsigned)(unsigned short)f2bf(hn)) << (16 * uu);
          }
          AT_ST((unsigned*)(P.H1b + ((size_t)bufA * 8 + g) * 16384 + fragidx(m, slice * 16 + u0)), pack);
        }
        float sr = hnv[0] + hnv[1], qr = hnv[0] * hnv[0] + hnv[1] * hnv[1];
        sr += __shfl_down(sr, 4, 8); qr += __shfl_down(qr, 4, 8);
        sr += __shfl_down(sr, 2, 8); qr += __shfl_down(qr, 2, 8);
        sr += __shfl_down(sr, 1, 8); qr += __shfl_down(qr, 1, 8);
        if ((idx & 7) == 0) {
          ull pv = ((ull)__float_as_uint(qr) << 32) | __float_as_uint(sr);
          ull* sp = isL0
              ? ((ull*)(P.St0 + ((size_t)bufB * 8 + g) * 2048) + m * 32 + slice)
              : ((ull*)(P.St1 + ((size_t)bufA * 8 + g) * 2048) + m * 32 + slice);
          AT_ST(sp, pv);
        }
      }
    }
    __syncthreads();   // combine-bar: vmcnt drained -> all H/St stores visible

    // ---- flag post + head (off critical path) ----
    if (tid == 0 && r <= T_STEPS) {
      AT_ST(P.flag0 + g * 32 + slice, (unsigned)(r + 1));
    }
    if (wid == 7 && r >= 2) {
      const int msam = slice;
      short8 hv8 = *(const short8*)(h1s + fragidx(msam, lane * 8));
      float lg[10];
      #pragma unroll
      for (int c = 0; c < 10; ++c) lg[c] = 0.f;
      #pragma unroll
      for (int kk = 0; kk < 8; ++kk) {
        float hv = bf2f(hv8[kk]);
        const float* wf = wfl + kk * 640 + lane;
        #pragma unroll
        for (int c = 0; c < 10; ++c) lg[c] += hv * wf[c * 64];
      }
      #pragma unroll
      for (int off = 32; off > 0; off >>= 1)
        #pragma unroll
        for (int c = 0; c < 10; ++c) lg[c] += __shfl_down(lg[c], off, 64);
      if (lane == 0) {
        float logit[10], mx = -1e30f;
        #pragma unroll
        for (int c = 0; c < 10; ++c) {
          logit[c] = r1r * lg[c] + ufl[c] - m1r * r1r * ufl[16 + c];
          mx = fmaxf(mx, logit[c]);
        }
        float ssum = 0.f;
        #pragma unroll
        for (int c = 0; c < 10; ++c) { logit[c] = expf(logit[c] - mx); ssum += logit[c]; }
        float inv = 1.f / ssum;
        float* op = P.out + ((size_t)(gm0 + msam) * T_STEPS + (r - 2)) * 10;
        #pragma unroll
        for (int c = 0; c < 10; ++c) op[c] = logit[c] * inv;
      }
    }
  }
}

extern "C" void kernel_launch(void* const* d_in, const int* in_sizes, int n_in,
                              void* d_out, int out_size, void* d_ws, size_t ws_size,
                              hipStream_t stream) {
  const float* x    = (const float*)d_in[0];
  const float* tms  = (const float*)d_in[1];
  const float* W0   = (const float*)d_in[2];
  const float* R0   = (const float*)d_in[3];
  const float* b0   = (const float*)d_in[4];
  const float* tau0 = (const float*)d_in[5];
  const float* s0   = (const float*)d_in[6];
  const float* g0   = (const float*)d_in[7];
  const float* be0  = (const float*)d_in[8];
  const float* W1   = (const float*)d_in[9];
  const float* R1   = (const float*)d_in[10];
  const float* b1   = (const float*)d_in[11];
  const float* tau1 = (const float*)d_in[12];
  const float* s1   = (const float*)d_in[13];
  const float* g1   = (const float*)d_in[14];
  const float* be1  = (const float*)d_in[15];
  const float* Wf   = (const float*)d_in[16];
  const float* bfv  = (const float*)d_in[17];

  char* ws = (char*)d_ws;
  short* Wswz = (short*)(ws + OFF_WSWZ);
  float* u1m  = (float*)(ws + OFF_U1);
  float* v1m  = (float*)(ws + OFF_V1);
  float* Wfpm = (float*)(ws + OFF_WFP);
  float* ufvm = (float*)(ws + OFF_UFV);

  Ptrs P;
  P.x = x; P.times = tms; P.W0 = W0; P.b0 = b0; P.tau0 = tau0; P.s0 = s0;
  P.b1 = b1; P.tau1 = tau1; P.s1 = s1;
  P.u1v = u1m; P.v1v = v1m; P.Wfp = Wfpm; P.ufv = ufvm;
  P.H0b = (short*)(ws + OFF_H0B);
  P.H1b = (short*)(ws + OFF_H1B);
  P.St0 = (float*)(ws + OFF_ST0);
  P.St1 = (float*)(ws + OFF_ST1);
  P.flag0 = (unsigned*)(ws + OFF_FLG0);
  P.flag1 = (unsigned*)(ws + OFF_FLG1);
  P.out = (float*)d_out;

  hipFuncSetAttribute(reinterpret_cast<const void*>(plstm_persist),
                      hipFuncAttributeMaxDynamicSharedMemorySize, SMEM_BYTES);

  prep_weights<<<1536, 256, 0, stream>>>(R0, W1, R1, g0, Wswz);
  prep_vecs<<<8, 256, 0, stream>>>(W1, g0, be0, u1m, v1m);
  prep_head<<<20, 256, 0, stream>>>(Wf, g1, be1, bfv, Wfpm, ufvm);
  hipMemsetAsync(ws + OFF_H0B, 0, ZERO_BYTES, stream);
  plstm_persist<<<NB, NTHR, SMEM_BYTES, stream>>>(P, Wswz);
}

// Round 13
// 5572.797 us; speedup vs baseline: 1.3035x; 1.0587x over previous
//
#include <hip/hip_runtime.h>
#include <hip/hip_bf16.h>

// PhasedLSTM classifier: persistent cooperative kernel (R9 skeleton).
// 8 groups (32 samples) x 32 slices (16 units) = 256 blocks (1/CU), 6 waves.
// R13 delta vs R9: H-state stores widened 4B -> 16B (shfl-gather to lanes
// 0/4 of each 8-thread sample group, global_store_dwordx4 sc1) to kill
// HBM partial-sector RMW on the agent-scope store path.
// Round r computes L0 step r, L1 step r-1, head step r-2.

#define NB 256
#define NTHR 384
#define T_STEPS 500
#define RON 0.05f
#define ALPHA_LEAK 1e-3f

typedef short short8 __attribute__((ext_vector_type(8)));
typedef float f32x4 __attribute__((ext_vector_type(4)));
typedef int int4v __attribute__((ext_vector_type(4)));
typedef unsigned long long ull;

// ---------------- ws layout (bytes) ----------------
#define OFF_WSWZ 0u              // 6291456  swizzled bf16 weights
#define OFF_U1   6291456u        // 8192
#define OFF_V1   6299648u        // 8192
#define OFF_WFP  6307840u        // 20480    Wf' permuted [kk][c][lane] f32
#define OFF_UFV  6328320u        // 128
#define OFF_H0B  6328448u        // 524288   [2][8][16384] bf16, frag order
#define OFF_H1B  6852736u        // 524288
#define OFF_ST0  7377024u        // 131072   [2][8][32 m][32 sl][2] f32
#define OFF_ST1  7508096u        // 131072
#define OFF_FLG0 7639168u        // 1024     [8][32] u32 round flags
#define OFF_FLG1 7640192u        // 1024     (unused, zeroed)
#define ZERO_BYTES 1312768u

// ---------------- LDS layout (bytes) ----------------
// 0      h0b            32768
// 32768  h1bL[2]        65536
// 98304  zbv            25728   (3 x [32][67] f32)
// 124032 mus              512   (mu0,rs0,mu1,rs1 x 32)
// 124544 xtb              640   (x0..x2,t x32 + t1 x32)
// 125184 prm             2048
// 127232 wfl            20480   ([kk][c][64] f32, conflict-free)
// 147712 ufl              128
#define SMEM_BYTES 147968

#define AT_LD(p)    __hip_atomic_load((p), __ATOMIC_RELAXED, __HIP_MEMORY_SCOPE_AGENT)
#define AT_ST(p, v) __hip_atomic_store((p), (v), __ATOMIC_RELAXED, __HIP_MEMORY_SCOPE_AGENT)

#define G2L(gp, lp) \
  __builtin_amdgcn_global_load_lds( \
      (const __attribute__((address_space(1))) void*)(gp), \
      (__attribute__((address_space(3))) void*)(lp), 16, 0, 16)

// 16B agent-scope store (same sc1 semantics AT_ST lowers to, 4x wider).
__device__ __forceinline__ void st_b128_sc1(void* p, int4v v) {
  asm volatile("global_store_dwordx4 %0, %1, off sc1" :: "v"(p), "v"(v) : "memory");
}

__device__ __forceinline__ short f2bf(float x) {
  unsigned u = __float_as_uint(x);
  unsigned r = (u + 0x7fffu + ((u >> 16) & 1u)) >> 16;
  return (short)r;
}
__device__ __forceinline__ float bf2f(short s) {
  return __uint_as_float(((unsigned)(unsigned short)s) << 16);
}
__device__ __forceinline__ float sigm(float x) { return 1.f / (1.f + __expf(-x)); }
__device__ __forceinline__ float tanh_f(float x) {
  float cx = fminf(fmaxf(x, -15.f), 15.f);
  float e = __expf(2.f * cx);
  return (e - 1.f) / (e + 1.f);
}
__device__ __forceinline__ float timegate(float t, float tau, float s) {
  float phi = fmodf(t - s, tau);
  if (phi < 0.f) phi += tau;
  phi /= tau;
  return phi < 0.5f * RON ? (2.f / RON) * phi
       : (phi < RON ? 2.f - (2.f / RON) * phi : ALPHA_LEAK * phi);
}
// element index (shorts) of (sample m<32, unit k) in a [32][512] bf16 buffer
// stored in 16x16x32-MFMA A-fragment order.
__device__ __forceinline__ int fragidx(int m, int k) {
  return ((((k >> 5) * 2 + (m >> 4)) * 64) + (((k >> 3) & 3) * 16) + (m & 15)) * 8 + (k & 7);
}

// ---------------- prep kernels ----------------
__global__ void prep_weights(const float* __restrict__ R0, const float* __restrict__ W1,
                             const float* __restrict__ R1, const float* __restrict__ g0,
                             short* __restrict__ Wswz) {
  int t = blockIdx.x * 256 + threadIdx.x;   // < 393216
  int lane = t & 63; int rest = t >> 6;
  int nf = rest & 1;  rest >>= 1;
  int kb = rest & 15; rest >>= 4;
  int ch = rest & 1;  rest >>= 1;
  int mm = rest % 3;  int slice = rest / 3;
  int c = ch * 32 + nf * 16 + (lane & 15);
  int gate = c >> 4;
  int unit = slice * 16 + (c & 15);
  int gcol = gate * 512 + unit;
  int k0 = kb * 32 + (lane >> 4) * 8;
  const float* src = (mm == 0) ? R0 : (mm == 1 ? W1 : R1);
  short8 o;
  #pragma unroll
  for (int e = 0; e < 8; ++e) {
    float v = src[(size_t)(k0 + e) * 2048 + gcol];
    if (mm == 1) v *= g0[k0 + e];
    o[e] = f2bf(v);
  }
  *(short8*)(Wswz + (size_t)t * 8) = o;
}

__global__ void prep_vecs(const float* __restrict__ W1, const float* __restrict__ g0,
                          const float* __restrict__ be0,
                          float* __restrict__ u1, float* __restrict__ v1) {
  int c = blockIdx.x * 256 + threadIdx.x;  // < 2048
  float su = 0.f, sv = 0.f;
  for (int k = 0; k < 512; ++k) {
    float w = W1[(size_t)k * 2048 + c];
    su += be0[k] * w; sv += g0[k] * w;
  }
  u1[c] = su; v1[c] = sv;
}

__global__ void prep_head(const float* __restrict__ Wf, const float* __restrict__ g1,
                          const float* __restrict__ be1, const float* __restrict__ bfv,
                          float* __restrict__ Wfp, float* __restrict__ ufv) {
  int t = blockIdx.x * 256 + threadIdx.x;
  if (t < 5120) {
    int kk = t / 640, rem = t - kk * 640, c = rem >> 6, l = rem & 63;
    int k = 8 * l + kk;
    Wfp[t] = g1[k] * Wf[k * 10 + c];
  }
  if (t < 10) {
    float su = bfv[t], sv = 0.f;
    for (int k = 0; k < 512; ++k) {
      float w = Wf[k * 10 + t];
      su += be1[k] * w; sv += g1[k] * w;
    }
    ufv[t] = su; ufv[16 + t] = sv;
  }
}

// ---------------- persistent kernel ----------------
struct Ptrs {
  const float *x, *times, *W0, *b0, *tau0, *s0, *b1, *tau1, *s1;
  const float *u1v, *v1v, *Wfp, *ufv;
  short *H0b, *H1b;
  float *St0, *St1;
  unsigned *flag0, *flag1;
  float *out;
};

__launch_bounds__(NTHR, 1)
__global__ void plstm_persist(Ptrs P, const short* __restrict__ Wswz) {
  extern __shared__ char smem[];
  short* h0b  = (short*)smem;
  short* h1bL = (short*)(smem + 32768);
  float* zbv  = (float*)(smem + 98304);
  float* mus  = (float*)(smem + 124032);
  float* xtb  = (float*)(smem + 124544);
  float* prm  = (float*)(smem + 125184);
  float* wfl  = (float*)(smem + 127232);
  float* ufl  = (float*)(smem + 147712);

  const int tid = threadIdx.x;
  const int g = blockIdx.x & 7;
  const int slice = blockIdx.x >> 3;
  const int wid = tid >> 6, lane = tid & 63;
  const int mm = wid >> 1, ch = wid & 1;
  const int gm0 = g * 32;

  // ---- one-time LDS init: params + head weights ----
  for (int i = tid; i < 512; i += NTHR) {
    float v;
    if (i < 192)      { int f = i >> 6, c = i & 63; v = P.W0[f * 2048 + ((c >> 4) << 9) + slice * 16 + (c & 15)]; }
    else if (i < 256) { int c = i & 63; v = P.b0[((c >> 4) << 9) + slice * 16 + (c & 15)]; }
    else if (i < 320) { int c = i & 63; int gc = ((c >> 4) << 9) + slice * 16 + (c & 15);
                        v = P.b1[gc] + P.u1v[gc]; }
    else if (i < 384) { int c = i & 63; v = P.v1v[((c >> 4) << 9) + slice * 16 + (c & 15)]; }
    else if (i < 448) v = 0.f;
    else if (i < 464) v = P.tau0[slice * 16 + (i & 15)];
    else if (i < 480) v = P.s0[slice * 16 + (i & 15)];
    else if (i < 496) v = P.tau1[slice * 16 + (i & 15)];
    else              v = P.s1[slice * 16 + (i & 15)];
    prm[i] = v;
  }
  for (int i = tid; i < 5120; i += NTHR) wfl[i] = P.Wfp[i];
  if (tid < 32) ufl[tid] = P.ufv[tid];

  // ---- resident weights: 16 kb x 2 nf x short8 = 128 VGPRs ----
  short8 wr[16][2];
  {
    const short* wb = Wswz + ((((size_t)slice * 3 + mm) * 2 + ch) * 32 * 64) * 8;
    #pragma unroll
    for (int kb = 0; kb < 16; ++kb)
      #pragma unroll
      for (int nf = 0; nf < 2; ++nf) {
        wr[kb][nf] = *(const short8*)(wb + ((kb * 2 + nf) * 64 + lane) * 8);
        asm volatile("" : "+v"(wr[kb][nf]));   // value barrier vs remat
      }
  }
  // register-resident recurrent state (fixed item->thread mapping)
  float h0A0 = 0.f, h0A1 = 0.f, c0A0 = 0.f, c0A1 = 0.f;   // tid<256: L0 item tid
  float h1B0 = 0.f, h1B1 = 0.f, c1B0 = 0.f, c1B1 = 0.f;   // tid>=256: L1 item tid-256
  float h1C0 = 0.f, h1C1 = 0.f, c1C0 = 0.f, c1C1 = 0.f;   // tid<128:  L1 item 128+tid
  __syncthreads();

  for (int r = 0; r <= T_STEPS + 1; ++r) {
    const int bufA = (r + 1) & 1;
    const int bufB = r & 1;
    short* h1s = h1bL + bufB * 16384;

    // ---- wave0: unified flag poll; wave4: x/times prefetch ----
    if (wid == 0) {
      const unsigned tgt = (unsigned)r;
      const unsigned* fp = P.flag0 + g * 32 + (lane & 31);
      for (int it_ = 0; it_ < 100000; ++it_) {
        unsigned v = (lane < 32) ? AT_LD(fp) : 0xFFFFFFFFu;
        if (__all((int)(v >= tgt))) break;
        __builtin_amdgcn_s_sleep(1);
      }
    } else if (wid == 4) {
      int m = lane & 31;
      if (lane < 32) {
        int step = (r < T_STEPS) ? r : (T_STEPS - 1);
        const float* xp = P.x + ((size_t)(gm0 + m) * T_STEPS + step) * 3;
        xtb[m * 4 + 0] = xp[0];
        xtb[m * 4 + 1] = xp[1];
        xtb[m * 4 + 2] = xp[2];
        xtb[m * 4 + 3] = P.times[(size_t)(gm0 + m) * T_STEPS + step];
      } else {
        int s1_ = (r >= 1) ? (r - 1) : 0;
        if (s1_ > T_STEPS - 1) s1_ = T_STEPS - 1;
        xtb[128 + m] = P.times[(size_t)(gm0 + m) * T_STEPS + s1_];
      }
    }
    __syncthreads();                     // poll-bar

    // ---- stage: waves 0-3 DMA H -> LDS (16B/lane x16); wave5 stats ----
    if (tid < 256) {
      const char* gA = (const char*)(P.H0b + ((size_t)bufA * 8 + g) * 16384);
      const char* gB = (const char*)(P.H1b + ((size_t)bufB * 8 + g) * 16384);
      char* lA = (char*)h0b;
      char* lB = (char*)h1s;
      #pragma unroll
      for (int k = 0; k < 8; ++k) {
        size_t off = (size_t)(k * 256 + tid) * 16;
        G2L(gA + off, lA + off);
        G2L(gB + off, lB + off);
      }
    } else if (wid == 5) {   // LN stats finalize (lanes 0-31 L0, 32-63 L1)
      const int layer = lane >> 5, m = lane & 31;
      const float* base = layer ? (P.St1 + ((size_t)bufB * 8 + g) * 2048 + m * 64)
                                : (P.St0 + ((size_t)bufA * 8 + g) * 2048 + m * 64);
      const ull* bu = (const ull*)base;
      float s_ = 0.f, q_ = 0.f;
      #pragma unroll
      for (int sl = 0; sl < 32; ++sl) {
        ull v = AT_LD(bu + sl);
        s_ += __uint_as_float((unsigned)v);
        q_ += __uint_as_float((unsigned)(v >> 32));
      }
      float mu = s_ * (1.f / 512.f);
      float var = q_ * (1.f / 512.f) - mu * mu;
      float rs = rsqrtf(var + 1e-3f);
      mus[layer * 64 + m] = mu;
      mus[layer * 64 + 32 + m] = rs;
    }
    __syncthreads();                     // stage-bar: drains DMA
    float m1r = 0.f, r1r = 0.f;
    if (wid == 1) { m1r = mus[64 + slice]; r1r = mus[96 + slice]; }  // hoist

    // ---- MFMA: z-slice = A @ Wslice ----
    if (r <= T_STEPS) {
      f32x4 acc[2][2] = {};
      const short* asrc = (mm == 2) ? h1s : h0b;
      #pragma unroll
      for (int kb = 0; kb < 16; ++kb) {
        short8 a0 = *(const short8*)(asrc + ((kb * 2 + 0) * 64 + lane) * 8);
        short8 a1 = *(const short8*)(asrc + ((kb * 2 + 1) * 64 + lane) * 8);
        #pragma unroll
        for (int nf = 0; nf < 2; ++nf) {
          acc[0][nf] = __builtin_amdgcn_mfma_f32_16x16x32_bf16(a0, wr[kb][nf], acc[0][nf], 0, 0, 0);
          acc[1][nf] = __builtin_amdgcn_mfma_f32_16x16x32_bf16(a1, wr[kb][nf], acc[1][nf], 0, 0, 0);
        }
      }
      float* z = zbv + mm * 2144;
      #pragma unroll
      for (int mf = 0; mf < 2; ++mf)
        #pragma unroll
        for (int nf = 0; nf < 2; ++nf)
          #pragma unroll
          for (int q = 0; q < 4; ++q) {
            int row = mf * 16 + (lane >> 4) * 4 + q;
            int col = ch * 32 + nf * 16 + (lane & 15);
            z[row * 67 + col] = acc[mf][nf][q];
          }
    }
    __syncthreads();                     // z-bar

    // ---- combine: gates + cell/phase updates, 16B widened H stores ----
    const bool l0act = (r < T_STEPS);
    const bool l1act = (r >= 1 && r <= T_STEPS);
    if (tid < 256 && l0act) {            // layer 0: 8 threads per sample
      int m = tid >> 3, u0 = (tid & 7) << 1;
      float x0 = xtb[m * 4 + 0], x1 = xtb[m * 4 + 1], x2 = xtb[m * 4 + 2];
      float tmv = xtb[m * 4 + 3];
      unsigned pack = 0; float hnv[2];
      #pragma unroll
      for (int uu = 0; uu < 2; ++uu) {
        int u = u0 + uu;
        float zg[4];
        #pragma unroll
        for (int q = 0; q < 4; ++q) {
          int c = q * 16 + u;
          zg[q] = zbv[m * 67 + c] + prm[192 + c]
                + x0 * prm[c] + x1 * prm[64 + c] + x2 * prm[128 + c];
        }
        float iv = sigm(zg[0]), fv = sigm(zg[1]), gv = tanh_f(zg[2]), ov = sigm(zg[3]);
        float cold = uu ? c0A1 : c0A0, hold = uu ? h0A1 : h0A0;
        float cp = fv * cold + iv * gv;
        float hp = ov * tanh_f(cp);
        float k = timegate(tmv, prm[448 + u], prm[464 + u]);
        float hn = k * hp + (1.f - k) * hold;
        float cn = k * cp + (1.f - k) * cold;
        if (uu) { h0A1 = hn; c0A1 = cn; } else { h0A0 = hn; c0A0 = cn; }
        hnv[uu] = hn;
        pack |= ((unsigned)(unsigned short)f2bf(hn)) << (16 * uu);
      }
      {  // gather 4 packs -> one 16B store on lanes 0/4 of each 8-group
        int l6 = tid & 63, b8 = l6 & ~7, half = l6 & 4;
        int4v d;
        d[0] = (int)__shfl(pack, b8 + half + 0, 64);
        d[1] = (int)__shfl(pack, b8 + half + 1, 64);
        d[2] = (int)__shfl(pack, b8 + half + 2, 64);
        d[3] = (int)__shfl(pack, b8 + half + 3, 64);
        if ((l6 & 3) == 0) {
          int kbase = slice * 16 + (half << 1);   // half=4 -> +8 units
          st_b128_sc1(P.H0b + ((size_t)bufB * 8 + g) * 16384 + fragidx(m, kbase), d);
        }
      }
      float sr = hnv[0] + hnv[1], qr = hnv[0] * hnv[0] + hnv[1] * hnv[1];
      sr += __shfl_down(sr, 4, 8); qr += __shfl_down(qr, 4, 8);
      sr += __shfl_down(sr, 2, 8); qr += __shfl_down(qr, 2, 8);
      sr += __shfl_down(sr, 1, 8); qr += __shfl_down(qr, 1, 8);
      if ((tid & 7) == 0) {
        ull pv = ((ull)__float_as_uint(qr) << 32) | __float_as_uint(sr);
        AT_ST((ull*)(P.St0 + ((size_t)bufB * 8 + g) * 2048) + m * 32 + slice, pv);
      }
    }
    #pragma unroll
    for (int pass = 0; pass < 2; ++pass) {  // layer 1 over 256 items on 384 thr
      int idx = -1;
      if (pass == 0 && tid >= 256) idx = tid - 256;
      if (pass == 1 && tid < 128)  idx = 128 + tid;
      if (idx >= 0 && l1act) {
        int m = idx >> 3, u0 = (idx & 7) << 1;
        float mu0m = mus[m], rs0m = mus[32 + m];
        float tmv = xtb[128 + m];
        unsigned pack = 0; float hnv[2];
        #pragma unroll
        for (int uu = 0; uu < 2; ++uu) {
          int u = u0 + uu;
          float zg[4];
          #pragma unroll
          for (int q = 0; q < 4; ++q) {
            int c = q * 16 + u;
            float zA = zbv[2144 + m * 67 + c];   // h0 @ (g0.W1)
            float zB = zbv[4288 + m * 67 + c];   // h1 @ R1
            zg[q] = rs0m * zA + zB + prm[256 + c] - mu0m * rs0m * prm[320 + c];
          }
          float iv = sigm(zg[0]), fv = sigm(zg[1]), gv = tanh_f(zg[2]), ov = sigm(zg[3]);
          float cold, hold;
          if (pass == 0) { cold = uu ? c1B1 : c1B0; hold = uu ? h1B1 : h1B0; }
          else           { cold = uu ? c1C1 : c1C0; hold = uu ? h1C1 : h1C0; }
          float cp = fv * cold + iv * gv;
          float hp = ov * tanh_f(cp);
          float k = timegate(tmv, prm[480 + u], prm[496 + u]);
          float hn = k * hp + (1.f - k) * hold;
          float cn = k * cp + (1.f - k) * cold;
          if (pass == 0) { if (uu) { h1B1 = hn; c1B1 = cn; } else { h1B0 = hn; c1B0 = cn; } }
          else           { if (uu) { h1C1 = hn; c1C1 = cn; } else { h1C0 = hn; c1C0 = cn; } }
          hnv[uu] = hn;
          pack |= ((unsigned)(unsigned short)f2bf(hn)) << (16 * uu);
        }
        {  // widened 16B store (lanes 0/4 of each 8-group)
          int l6 = tid & 63, b8 = l6 & ~7, half = l6 & 4;
          int4v d;
          d[0] = (int)__shfl(pack, b8 + half + 0, 64);
          d[1] = (int)__shfl(pack, b8 + half + 1, 64);
          d[2] = (int)__shfl(pack, b8 + half + 2, 64);
          d[3] = (int)__shfl(pack, b8 + half + 3, 64);
          if ((l6 & 3) == 0) {
            int kbase = slice * 16 + (half << 1);
            st_b128_sc1(P.H1b + ((size_t)bufA * 8 + g) * 16384 + fragidx(m, kbase), d);
          }
        }
        float sr = hnv[0] + hnv[1], qr = hnv[0] * hnv[0] + hnv[1] * hnv[1];
        sr += __shfl_down(sr, 4, 8); qr += __shfl_down(qr, 4, 8);
        sr += __shfl_down(sr, 2, 8); qr += __shfl_down(qr, 2, 8);
        sr += __shfl_down(sr, 1, 8); qr += __shfl_down(qr, 1, 8);
        if ((idx & 7) == 0) {
          ull pv = ((ull)__float_as_uint(qr) << 32) | __float_as_uint(sr);
          AT_ST((ull*)(P.St1 + ((size_t)bufA * 8 + g) * 2048) + m * 32 + slice, pv);
        }
      }
    }
    __syncthreads();   // combine-bar: vmcnt drained -> all H/St stores visible

    // ---- flag post (head overlaps next round's poll) ----
    if (tid == 0 && r <= T_STEPS) {
      AT_ST(P.flag0 + g * 32 + slice, (unsigned)(r + 1));
    }
    // ---- classifier head for step r-2 (wave 1) ----
    if (wid == 1 && r >= 2) {
      int msam = slice;
      short8 hv8 = *(const short8*)(h1s + fragidx(msam, lane * 8));
      float lg[10];
      #pragma unroll
      for (int c = 0; c < 10; ++c) lg[c] = 0.f;
      #pragma unroll
      for (int kk = 0; kk < 8; ++kk) {
        float hv = bf2f(hv8[kk]);
        const float* wf = wfl + kk * 640 + lane;
        #pragma unroll
        for (int c = 0; c < 10; ++c) lg[c] += hv * wf[c * 64];
      }
      #pragma unroll
      for (int off = 32; off > 0; off >>= 1)
        #pragma unroll
        for (int c = 0; c < 10; ++c) lg[c] += __shfl_down(lg[c], off, 64);
      if (lane == 0) {
        float logit[10], mx = -1e30f;
        #pragma unroll
        for (int c = 0; c < 10; ++c) {
          logit[c] = r1r * lg[c] + ufl[c] - m1r * r1r * ufl[16 + c];
          mx = fmaxf(mx, logit[c]);
        }
        float ssum = 0.f;
        #pragma unroll
        for (int c = 0; c < 10; ++c) { logit[c] = expf(logit[c] - mx); ssum += logit[c]; }
        float inv = 1.f / ssum;
        float* op = P.out + ((size_t)(gm0 + msam) * T_STEPS + (r - 2)) * 10;
        #pragma unroll
        for (int c = 0; c < 10; ++c) op[c] = logit[c] * inv;
      }
    }
  }
}

extern "C" void kernel_launch(void* const* d_in, const int* in_sizes, int n_in,
                              void* d_out, int out_size, void* d_ws, size_t ws_size,
                              hipStream_t stream) {
  const float* x    = (const float*)d_in[0];
  const float* tms  = (const float*)d_in[1];
  const float* W0   = (const float*)d_in[2];
  const float* R0   = (const float*)d_in[3];
  const float* b0   = (const float*)d_in[4];
  const float* tau0 = (const float*)d_in[5];
  const float* s0   = (const float*)d_in[6];
  const float* g0   = (const float*)d_in[7];
  const float* be0  = (const float*)d_in[8];
  const float* W1   = (const float*)d_in[9];
  const float* R1   = (const float*)d_in[10];
  const float* b1   = (const float*)d_in[11];
  const float* tau1 = (const float*)d_in[12];
  const float* s1   = (const float*)d_in[13];
  const float* g1   = (const float*)d_in[14];
  const float* be1  = (const float*)d_in[15];
  const float* Wf   = (const float*)d_in[16];
  const float* bfv  = (const float*)d_in[17];

  char* ws = (char*)d_ws;
  short* Wswz = (short*)(ws + OFF_WSWZ);
  float* u1m  = (float*)(ws + OFF_U1);
  float* v1m  = (float*)(ws + OFF_V1);
  float* Wfpm = (float*)(ws + OFF_WFP);
  float* ufvm = (float*)(ws + OFF_UFV);

  Ptrs P;
  P.x = x; P.times = tms; P.W0 = W0; P.b0 = b0; P.tau0 = tau0; P.s0 = s0;
  P.b1 = b1; P.tau1 = tau1; P.s1 = s1;
  P.u1v = u1m; P.v1v = v1m; P.Wfp = Wfpm; P.ufv = ufvm;
  P.H0b = (short*)(ws + OFF_H0B);
  P.H1b = (short*)(ws + OFF_H1B);
  P.St0 = (float*)(ws + OFF_ST0);
  P.St1 = (float*)(ws + OFF_ST1);
  P.flag0 = (unsigned*)(ws + OFF_FLG0);
  P.flag1 = (unsigned*)(ws + OFF_FLG1);
  P.out = (float*)d_out;

  hipFuncSetAttribute(reinterpret_cast<const void*>(plstm_persist),
                      hipFuncAttributeMaxDynamicSharedMemorySize, SMEM_BYTES);

  prep_weights<<<1536, 256, 0, stream>>>(R0, W1, R1, g0, Wswz);
  prep_vecs<<<8, 256, 0, stream>>>(W1, g0, be0, u1m, v1m);
  prep_head<<<20, 256, 0, stream>>>(Wf, g1, be1, bfv, Wfpm, ufvm);
  hipMemsetAsync(ws + OFF_H0B, 0, ZERO_BYTES, stream);
  plstm_persist<<<NB, NTHR, SMEM_BYTES, stream>>>(P, Wswz);
}